// Round 6
// baseline (171.938 us; speedup 1.0000x reference)
//
#include <hip/hip_runtime.h>

// Problem: B=2, S=2048, D=1024, H=16, HD=64. fp32 in/out.
// Pipeline exploits head-summed K/V: k_sum = x @ (sum_h Wk_h)^T + sum_h bk_h.
//  1. prep_all:    x, Wout -> f16; wcomb = [Wq; Wred] f16 (1152x1024); bcomb
//  2. gemm_t3<0>:  [Q*scale | k_sum | v_sum^T] = x @ wcomb^T + bcomb (N=1152)
//  3. flash_attn12: 8 rows/block, 1 wave = 1 full s-row, 128-t batched
//                  softmax; XCD-dispatch-aware pairing (17 units/CU)
//  4. gemm_t3<1>:  out = ao @ Wout^T + bout   (4096x1024x1024) -> f32
// gemm_t3 = m97 tile with DOUBLE-BUFFERED LDS, 2-phase K-loop (T3-minimum):
// STAGE(next) issued before compute(cur), single barrier per K-step, so the
// vmcnt drain at the barrier lands after MFMA has covered the load latency.
// This targets solo-block efficiency (grids 288/256 leave ~1 block/CU).

#define S_LEN 2048
#define DIM 1024

using floatx4 = __attribute__((ext_vector_type(4))) float;
using halfx8  = __attribute__((ext_vector_type(8))) _Float16;
using halfx4  = __attribute__((ext_vector_type(4))) _Float16;

__device__ __forceinline__ floatx4 mfma16(halfx8 a, halfx8 b, floatx4 c) {
  return __builtin_amdgcn_mfma_f32_16x16x32_f16(a, b, c, 0, 0, 0);
}

// async global->LDS, 16B per lane; lds dst is wave-uniform base + lane*16
__device__ __forceinline__ void gll16(const void* g, void* l) {
  __builtin_amdgcn_global_load_lds(
      (const __attribute__((address_space(1))) void*)g,
      (__attribute__((address_space(3))) void*)l, 16, 0, 0);
}

// ---------------- prep: conversions + combined weights ----------------
__global__ __launch_bounds__(256) void prep_all(
    const float* __restrict__ x, const float* __restrict__ wqkv,
    const float* __restrict__ bqkv, const float* __restrict__ wout,
    _Float16* __restrict__ xb, _Float16* __restrict__ wcomb,
    _Float16* __restrict__ woutb, float* __restrict__ bcomb) {
  int bx = blockIdx.x;
  if (bx < 6144) {
    size_t i4 = ((size_t)bx * 256 + threadIdx.x) * 4;
    const float* src;
    _Float16* dst;
    size_t off;
    if (i4 < 4194304) { src = x; dst = xb; off = i4; }
    else if (i4 < 5242880) { src = wqkv; dst = wcomb; off = i4 - 4194304; }
    else { src = wout; dst = woutb; off = i4 - 5242880; }
    float4 v = *(const float4*)(src + off);
    halfx4 o;
    o[0] = (_Float16)v.x; o[1] = (_Float16)v.y;
    o[2] = (_Float16)v.z; o[3] = (_Float16)v.w;
    *(halfx4*)(dst + off) = o;
  } else {
    int gid = (bx - 6144) * 256 + threadIdx.x;  // 131072 threads
    int c = gid >> 10, j = gid & 1023;
    int row0 = (c < 64) ? (1024 + c) : (2048 + c - 64);
    float s = 0.f;
#pragma unroll
    for (int h = 0; h < 16; ++h) s += wqkv[(size_t)(row0 + h * 64) * 1024 + j];
    wcomb[(size_t)1024 * 1024 + gid] = (_Float16)s;
    if (gid < 1024) bcomb[gid] = bqkv[gid];
    if (gid < 128) {
      int b0 = (gid < 64) ? (1024 + gid) : (2048 + gid - 64);
      float sb = 0.f;
#pragma unroll
      for (int h = 0; h < 16; ++h) sb += bqkv[b0 + h * 64];
      bcomb[1024 + gid] = sb;
    }
  }
}

// ---- gemm_t3: 128M x 128N tile, BK=64, double-buffered 2-phase K-loop ----
// Wave w -> 64x64 quadrant: rows (w&1)*64, cols (w>>1)*64; 4x4 16x16 frags.
// gll16 staging with XOR col-group swizzle (row r group g at g^(r&7)).
// K-step: STAGE(buf^1, kt+64) issue -> compute(buf) -> barrier (drain lands
// after MFMA covered the latency) -> swap. One barrier/step.
// MODE 0: N=1152 fused epilogue -> qb (*scale), kb, vtb(V^T). MODE 1: f32 out.
template <int MODE>
__global__ __launch_bounds__(256, 2) void gemm_t3(
    const _Float16* __restrict__ A, const _Float16* __restrict__ W,
    const float* __restrict__ bias, void* __restrict__ Cv,
    _Float16* __restrict__ kbo, _Float16* __restrict__ vto) {
  const int K = 1024;
  __shared__ _Float16 As[2][128][64];  // 32 KB
  __shared__ _Float16 Ws[2][128][64];  // 32 KB
  int tid = threadIdx.x;
  int lane = tid & 63, w = tid >> 6, ln = lane & 15, q4 = lane >> 4;
  int m0 = blockIdx.x * 128, n0 = blockIdx.y * 128;
  int mh = (w & 1) * 64, nh = (w >> 1) * 64;
  int rr = lane >> 3, gg = ((lane & 7) ^ rr) * 8;  // staging lane row/col
  const _Float16* agp = A + (size_t)(m0 + w * 32 + rr) * K + gg;
  const _Float16* wgp = W + (size_t)(n0 + w * 32 + rr) * K + gg;
  floatx4 acc[4][4] = {};
  // prologue: stage kt=0 into buffer 0
#pragma unroll
  for (int j = 0; j < 4; ++j) {
    gll16(agp + (size_t)(8 * j) * K, &As[0][w * 32 + 8 * j][0]);
    gll16(wgp + (size_t)(8 * j) * K, &Ws[0][w * 32 + 8 * j][0]);
  }
  __syncthreads();
  int cur = 0;
  for (int kt = 0; kt < K; kt += 64) {
    int nxt = cur ^ 1;
    if (kt + 64 < K) {  // issue next-tile staging; flies under compute
#pragma unroll
      for (int j = 0; j < 4; ++j) {
        gll16(agp + (size_t)(8 * j) * K + kt + 64, &As[nxt][w * 32 + 8 * j][0]);
        gll16(wgp + (size_t)(8 * j) * K + kt + 64, &Ws[nxt][w * 32 + 8 * j][0]);
      }
    }
#pragma unroll
    for (int kh = 0; kh < 2; ++kh) {
      int sw = ((q4 + 4 * kh) ^ (ln & 7)) * 8;
      halfx8 bf[4];
#pragma unroll
      for (int nf = 0; nf < 4; ++nf)
        bf[nf] = *(const halfx8*)&Ws[cur][nh + nf * 16 + ln][sw];
#pragma unroll
      for (int mf = 0; mf < 4; ++mf) {
        halfx8 af = *(const halfx8*)&As[cur][mh + mf * 16 + ln][sw];
#pragma unroll
        for (int nf = 0; nf < 4; ++nf)
          acc[mf][nf] = mfma16(af, bf[nf], acc[mf][nf]);
      }
    }
    __syncthreads();  // drains prefetch (already landed) + guards buf reuse
    cur = nxt;
  }
  const float qscale = 0.18033688011112042f;  // (1/sqrt(64)) * log2(e)
#pragma unroll
  for (int nf = 0; nf < 4; ++nf) {
    int col = n0 + nh + nf * 16 + ln;
    float bv = bias[col];
    if constexpr (MODE == 1) {
#pragma unroll
      for (int mf = 0; mf < 4; ++mf)
#pragma unroll
        for (int i = 0; i < 4; ++i) {
          int row = m0 + mh + mf * 16 + q4 * 4 + i;
          ((float*)Cv)[(size_t)row * 1024 + col] = acc[mf][nf][i] + bv;
        }
    } else {
      if (col < 1024) {  // Q, pre-scaled for log2-domain softmax
#pragma unroll
        for (int mf = 0; mf < 4; ++mf)
#pragma unroll
          for (int i = 0; i < 4; ++i) {
            int row = m0 + mh + mf * 16 + q4 * 4 + i;
            ((_Float16*)Cv)[(size_t)row * 1024 + col] =
                (_Float16)((acc[mf][nf][i] + bv) * qscale);
          }
      } else if (col < 1088) {  // k_sum
        int ck = col - 1024;
#pragma unroll
        for (int mf = 0; mf < 4; ++mf)
#pragma unroll
          for (int i = 0; i < 4; ++i) {
            int row = m0 + mh + mf * 16 + q4 * 4 + i;
            kbo[(size_t)row * 64 + ck] = (_Float16)(acc[mf][nf][i] + bv);
          }
      } else {  // v_sum, transposed: vtb[(b*64+d)*S + s]
        int d = col - 1088;
#pragma unroll
        for (int mf = 0; mf < 4; ++mf) {
          int row0 = m0 + mh + mf * 16 + q4 * 4;
          int bb = row0 >> 11, sps = row0 & 2047;
          halfx4 o;
#pragma unroll
          for (int i = 0; i < 4; ++i) o[i] = (_Float16)(acc[mf][nf][i] + bv);
          *(halfx4*)&vto[((size_t)((bb << 6) + d)) * S_LEN + sps] = o;
        }
      }
    }
  }
}

// ---------------- flash v12: XCD-dispatch-aware chunk pairing --------------
// Block = 8 consecutive s-rows (one chunk), 8 waves, 1 wave = 1 full s-row.
// Per 128-t staged tile: 16 QK MFMA -> batched softmax (31-fmax tree, 32
// exp2, single defer-check) -> 16 PV MFMA. P reader-linear in LDS.
// Dispatch model (confirmed r4/r5: T = n_s*4.86 + (17-2n_s)*3.05, measured
// 50.6 = predicted pair(1,16) path): blocks (i, i+256) co-resident.
__global__ __launch_bounds__(512, 4) void flash_attn12(
    const _Float16* __restrict__ Qb, const _Float16* __restrict__ kb,
    const _Float16* __restrict__ vtb, _Float16* __restrict__ aob) {
  __shared__ _Float16 Ks[128][64];   // 16 KB  K tile [t][d], XOR-swizzled
  __shared__ _Float16 Vt[64][128];   // 16 KB  V^T tile [d][t], per-64-half swz
  __shared__ _Float16 Ps[8][2048];   // 32 KB  per-wave P, reader-linear
  int tid = threadIdx.x;
  int lane = tid & 63, w = tid >> 6, ln = lane & 15, q4 = lane >> 4;
  int bx = (int)blockIdx.x;
  int lo = bx & 255;
  int b = lo & 1;                               // batch
  int crow = (bx >> 8) ? (255 - (lo >> 1)) : (lo >> 1);  // row-chunk
  int s0 = crow * 8;
  int s = s0 + w;
  size_t bS = (size_t)b * S_LEN;

  // K staging: wave w covers t-rows w*16..+15; lane: row += lane>>3, grp^row
  int rr = lane >> 3, ggk = ((lane & 7) ^ rr) * 8;
  const _Float16* kgp = kb + (bS + w * 16 + rr) * 64 + ggk;
  // V staging: wave w covers d-rows w*8..+7; lane: row += lane>>4,
  // t-col = half*64 + (vg ^ (row&7))*8, vg = lane&7, half = (lane>>3)&1
  int vr = lane >> 4;
  int vhalf = (lane >> 3) & 1, vg = lane & 7;
  const _Float16* vgp[2];
#pragma unroll
  for (int j = 0; j < 2; ++j) {
    int row = w * 8 + 4 * j + vr;
    vgp[j] = vtb + ((size_t)b * 64 + row) * S_LEN + vhalf * 64 +
             ((vg ^ (row & 7)) * 8);
  }
  int swk0 = (q4 ^ (ln & 7)) * 8;
  int swk1 = ((q4 + 4) ^ (ln & 7)) * 8;
  _Float16* Pw = &Ps[w][0];
  // P write (halfx4): half-idx = (tq*8+tf*2)*128 + pwbase
  int pwbase = (q4 >> 1) * 128 + ln * 8 + (q4 & 1) * 4;
  // P read (halfx8): half-idx = kc*512 + prbase  (lane-linear)
  int prbase = q4 * 128 + ln * 8;

  const _Float16* qp = Qb + (bS + s) * DIM + ln * 64 + q4 * 8;
  halfx8 bq0 = *(const halfx8*)qp, bq1 = *(const halfx8*)(qp + 32);

  float m_run = -1e30f, l_run = 0.f;
  floatx4 oacc[4] = {};
  int nt = (crow >> 4) + 1;

  for (int it = 0; it < nt; ++it) {
    int t0 = it << 7;
    __syncthreads();
    gll16(kgp + (size_t)t0 * 64, &Ks[w * 16][0]);
    gll16(kgp + (size_t)(t0 + 8) * 64, &Ks[w * 16 + 8][0]);
    gll16(vgp[0] + t0, &Vt[w * 8][0]);
    gll16(vgp[1] + t0, &Vt[w * 8 + 4][0]);
    __syncthreads();

    // S^T = K Q^T (log2 domain): frag (tq,tf) rows t = t0+tq*64+tf*16+ln
    floatx4 sf[2][4];
    __builtin_amdgcn_s_setprio(1);
#pragma unroll
    for (int tq = 0; tq < 2; ++tq)
#pragma unroll
      for (int tf = 0; tf < 4; ++tf) {
        halfx8 ak0 = *(const halfx8*)&Ks[tq * 64 + tf * 16 + ln][swk0];
        halfx8 ak1 = *(const halfx8*)&Ks[tq * 64 + tf * 16 + ln][swk1];
        floatx4 z = {};
        z = mfma16(ak0, bq0, z);
        sf[tq][tf] = mfma16(ak1, bq1, z);
      }
    __builtin_amdgcn_s_setprio(0);
    if (it == nt - 1) {  // causal mask (block-uniform: only final tile)
#pragma unroll
      for (int tq = 0; tq < 2; ++tq)
#pragma unroll
        for (int tf = 0; tf < 4; ++tf)
#pragma unroll
          for (int i = 0; i < 4; ++i) {
            int t = t0 + tq * 64 + tf * 16 + q4 * 4 + i;
            if (t > s) sf[tq][tf][i] = -1e30f;
          }
    }
    // batched max over all 32 values
    float tm = -1e30f;
#pragma unroll
    for (int tq = 0; tq < 2; ++tq)
#pragma unroll
      for (int tf = 0; tf < 4; ++tf)
        tm = fmaxf(tm, fmaxf(fmaxf(sf[tq][tf][0], sf[tq][tf][1]),
                             fmaxf(sf[tq][tf][2], sf[tq][tf][3])));
    tm = fmaxf(tm, __shfl_xor(tm, 16));
    tm = fmaxf(tm, __shfl_xor(tm, 32));
    // defer-rescale (T13): skip O/l rescale while max drift <= 8 (log2)
    if (!__all(tm <= m_run + 8.f)) {
      float mn = fmaxf(m_run, tm);
      float alpha = exp2f(m_run - mn);
      m_run = mn;
      l_run *= alpha;
#pragma unroll
      for (int n2 = 0; n2 < 4; ++n2)
#pragma unroll
        for (int i = 0; i < 4; ++i) oacc[n2][i] *= alpha;
    }
    float rs = 0.f;
#pragma unroll
    for (int tq = 0; tq < 2; ++tq)
#pragma unroll
      for (int tf = 0; tf < 4; ++tf) {
        float p0 = exp2f(sf[tq][tf][0] - m_run);
        float p1 = exp2f(sf[tq][tf][1] - m_run);
        float p2 = exp2f(sf[tq][tf][2] - m_run);
        float p3 = exp2f(sf[tq][tf][3] - m_run);
        rs += (p0 + p1) + (p2 + p3);
        halfx4 pk;
        pk[0] = (_Float16)p0; pk[1] = (_Float16)p1;
        pk[2] = (_Float16)p2; pk[3] = (_Float16)p3;
        *(halfx4*)&Pw[(tq * 8 + tf * 2) * 128 + pwbase] = pk;
      }
    rs += __shfl_xor(rs, 16);
    rs += __shfl_xor(rs, 32);
    l_run += rs;
    // PV: O^T += V^T x P over 4 k-chunks of 32 t
    halfx8 bp[4];
#pragma unroll
    for (int kc = 0; kc < 4; ++kc)
      bp[kc] = *(const halfx8*)&Pw[kc * 512 + prbase];
    __builtin_amdgcn_s_setprio(1);
#pragma unroll
    for (int kc = 0; kc < 4; ++kc) {
      int half = (kc >> 1) * 64;
      int sw = ((q4 + 4 * (kc & 1)) ^ (ln & 7)) * 8;
#pragma unroll
      for (int n2 = 0; n2 < 4; ++n2) {
        halfx8 av = *(const halfx8*)&Vt[n2 * 16 + ln][half + sw];
        oacc[n2] = mfma16(av, bp[kc], oacc[n2]);
      }
    }
    __builtin_amdgcn_s_setprio(0);
  }
  // epilogue: O^T frag n2: h=ln, d=n2*16+q4*4+i (wave owns the full row)
  float inv = 1.0f / l_run;
#pragma unroll
  for (int n2 = 0; n2 < 4; ++n2) {
    halfx4 o;
#pragma unroll
    for (int i = 0; i < 4; ++i) o[i] = (_Float16)(oacc[n2][i] * inv);
    *(halfx4*)(aob + (bS + s) * DIM + ln * 64 + n2 * 16 + q4 * 4) = o;
  }
}

extern "C" void kernel_launch(void* const* d_in, const int* in_sizes, int n_in,
                              void* d_out, int out_size, void* d_ws,
                              size_t ws_size, hipStream_t stream) {
  const float* x    = (const float*)d_in[0];
  const float* wqkv = (const float*)d_in[1];
  const float* bqkv = (const float*)d_in[2];
  const float* wout = (const float*)d_in[3];
  const float* bout = (const float*)d_in[4];
  float* out = (float*)d_out;
  char* ws = (char*)d_ws;
  _Float16* xb    = (_Float16*)(ws);                               // 8 MB
  _Float16* qb    = (_Float16*)(ws + (8u << 20));                  // 8 MB
  _Float16* aob   = (_Float16*)(ws + (16u << 20));                 // 8 MB
  _Float16* kb    = (_Float16*)(ws + (24u << 20));                 // 512 KB
  _Float16* vtb   = (_Float16*)(ws + (24u << 20) + (512u << 10));  // 512 KB
  _Float16* wcomb = (_Float16*)(ws + (25u << 20));                 // 2.25 MB
  _Float16* woutb = (_Float16*)(ws + (27u << 20) + (512u << 10));  // 2 MB
  float*    bcomb = (float*)(ws + (29u << 20) + (512u << 10));     // 4.6 KB

  hipLaunchKernelGGL(prep_all, dim3(6656), dim3(256), 0, stream,
                     x, wqkv, bqkv, wout, xb, wcomb, woutb, bcomb);
  hipLaunchKernelGGL((gemm_t3<0>), dim3(32, 9), dim3(256), 0, stream,
                     xb, wcomb, bcomb, (void*)qb, kb, vtb);
  hipLaunchKernelGGL(flash_attn12, dim3(512), dim3(512), 0, stream,
                     qb, kb, vtb, aob);
  hipLaunchKernelGGL((gemm_t3<1>), dim3(32, 8), dim3(256), 0, stream,
                     aob, woutb, bout, (void*)out, nullptr, nullptr);
}

// Round 7
// 165.917 us; speedup vs baseline: 1.0363x; 1.0363x over previous
//
#include <hip/hip_runtime.h>

// Problem: B=2, S=2048, D=1024, H=16, HD=64. fp32 in/out.
// Pipeline exploits head-summed K/V: k_sum = x @ (sum_h Wk_h)^T + sum_h bk_h.
//  1. prep_all:    x, Wout -> f16; wcomb = [Wq; Wred] f16 (1152x1024); bcomb
//  2. gemm_t4<0>:  [Q*scale | k_sum | v_sum^T] = x @ wcomb^T + bcomb (N=1152)
//  3. flash_attn12: 8 rows/block, 1 wave = 1 full s-row, 128-t batched
//                  softmax; XCD-dispatch-aware pairing (17 units/CU)
//  4. gemm_t4<1>:  out = ao @ Wout^T + bout   (4096x1024x1024) -> f32
// gemm_t4 = m97 single-buffer 2-barrier loop, retiled 64M x 128N so the grid
// is 576/512 blocks -> 2-3 co-resident blocks/CU (was 1.125). Co-resident
// blocks hide each other's staging drain (dbuf attempt r6 was neutral,
// confirming the missing ingredient was TLP, not pipeline depth).

#define S_LEN 2048
#define DIM 1024

using floatx4 = __attribute__((ext_vector_type(4))) float;
using halfx8  = __attribute__((ext_vector_type(8))) _Float16;
using halfx4  = __attribute__((ext_vector_type(4))) _Float16;

__device__ __forceinline__ floatx4 mfma16(halfx8 a, halfx8 b, floatx4 c) {
  return __builtin_amdgcn_mfma_f32_16x16x32_f16(a, b, c, 0, 0, 0);
}

// async global->LDS, 16B per lane; lds dst is wave-uniform base + lane*16
__device__ __forceinline__ void gll16(const void* g, void* l) {
  __builtin_amdgcn_global_load_lds(
      (const __attribute__((address_space(1))) void*)g,
      (__attribute__((address_space(3))) void*)l, 16, 0, 0);
}

// ---------------- prep: conversions + combined weights ----------------
__global__ __launch_bounds__(256) void prep_all(
    const float* __restrict__ x, const float* __restrict__ wqkv,
    const float* __restrict__ bqkv, const float* __restrict__ wout,
    _Float16* __restrict__ xb, _Float16* __restrict__ wcomb,
    _Float16* __restrict__ woutb, float* __restrict__ bcomb) {
  int bx = blockIdx.x;
  if (bx < 6144) {
    size_t i4 = ((size_t)bx * 256 + threadIdx.x) * 4;
    const float* src;
    _Float16* dst;
    size_t off;
    if (i4 < 4194304) { src = x; dst = xb; off = i4; }
    else if (i4 < 5242880) { src = wqkv; dst = wcomb; off = i4 - 4194304; }
    else { src = wout; dst = woutb; off = i4 - 5242880; }
    float4 v = *(const float4*)(src + off);
    halfx4 o;
    o[0] = (_Float16)v.x; o[1] = (_Float16)v.y;
    o[2] = (_Float16)v.z; o[3] = (_Float16)v.w;
    *(halfx4*)(dst + off) = o;
  } else {
    int gid = (bx - 6144) * 256 + threadIdx.x;  // 131072 threads
    int c = gid >> 10, j = gid & 1023;
    int row0 = (c < 64) ? (1024 + c) : (2048 + c - 64);
    float s = 0.f;
#pragma unroll
    for (int h = 0; h < 16; ++h) s += wqkv[(size_t)(row0 + h * 64) * 1024 + j];
    wcomb[(size_t)1024 * 1024 + gid] = (_Float16)s;
    if (gid < 1024) bcomb[gid] = bqkv[gid];
    if (gid < 128) {
      int b0 = (gid < 64) ? (1024 + gid) : (2048 + gid - 64);
      float sb = 0.f;
#pragma unroll
      for (int h = 0; h < 16; ++h) sb += bqkv[b0 + h * 64];
      bcomb[1024 + gid] = sb;
    }
  }
}

// ---- gemm_t4: 64M x 128N tile, BK=64, single-buffer, 2 barriers/step ----
// Wave w owns cols w*32 (4 m-frags x 2 n-frags). Staging per wave/K-step:
// A rows w*16..+15 (2 gll16), W rows w*32..+31 (4 gll16); XOR col-group
// swizzle (row r group g at g^(r&7)). LDS 24 KB -> high co-residency.
// MODE 0: N=1152 fused epilogue -> qb (*scale), kb, vtb(V^T). MODE 1: f32 out.
template <int MODE>
__global__ __launch_bounds__(256, 3) void gemm_t4(
    const _Float16* __restrict__ A, const _Float16* __restrict__ W,
    const float* __restrict__ bias, void* __restrict__ Cv,
    _Float16* __restrict__ kbo, _Float16* __restrict__ vto) {
  const int K = 1024;
  __shared__ _Float16 As[64][64];   // 8 KB
  __shared__ _Float16 Ws[128][64];  // 16 KB
  int tid = threadIdx.x;
  int lane = tid & 63, w = tid >> 6, ln = lane & 15, q4 = lane >> 4;
  int m0 = blockIdx.x * 64, n0 = blockIdx.y * 128;
  int rr = lane >> 3, gg = ((lane & 7) ^ rr) * 8;  // staging lane row/col
  const _Float16* agp = A + (size_t)(m0 + w * 16 + rr) * K + gg;
  const _Float16* wgp = W + (size_t)(n0 + w * 32 + rr) * K + gg;
  floatx4 acc[4][2] = {};
  for (int kt = 0; kt < K; kt += 64) {
    __syncthreads();  // readers done with previous tile
#pragma unroll
    for (int j = 0; j < 2; ++j)
      gll16(agp + (size_t)(8 * j) * K + kt, &As[w * 16 + 8 * j][0]);
#pragma unroll
    for (int j = 0; j < 4; ++j)
      gll16(wgp + (size_t)(8 * j) * K + kt, &Ws[w * 32 + 8 * j][0]);
    __syncthreads();  // staging visible
#pragma unroll
    for (int kh = 0; kh < 2; ++kh) {
      int sw = ((q4 + 4 * kh) ^ (ln & 7)) * 8;
      halfx8 bf[2];
#pragma unroll
      for (int nf = 0; nf < 2; ++nf)
        bf[nf] = *(const halfx8*)&Ws[w * 32 + nf * 16 + ln][sw];
#pragma unroll
      for (int mf = 0; mf < 4; ++mf) {
        halfx8 af = *(const halfx8*)&As[mf * 16 + ln][sw];
#pragma unroll
        for (int nf = 0; nf < 2; ++nf)
          acc[mf][nf] = mfma16(af, bf[nf], acc[mf][nf]);
      }
    }
  }
  const float qscale = 0.18033688011112042f;  // (1/sqrt(64)) * log2(e)
#pragma unroll
  for (int nf = 0; nf < 2; ++nf) {
    int col = n0 + w * 32 + nf * 16 + ln;
    float bv = bias[col];
    if constexpr (MODE == 1) {
#pragma unroll
      for (int mf = 0; mf < 4; ++mf)
#pragma unroll
        for (int i = 0; i < 4; ++i) {
          int row = m0 + mf * 16 + q4 * 4 + i;
          ((float*)Cv)[(size_t)row * 1024 + col] = acc[mf][nf][i] + bv;
        }
    } else {
      if (col < 1024) {  // Q, pre-scaled for log2-domain softmax
#pragma unroll
        for (int mf = 0; mf < 4; ++mf)
#pragma unroll
          for (int i = 0; i < 4; ++i) {
            int row = m0 + mf * 16 + q4 * 4 + i;
            ((_Float16*)Cv)[(size_t)row * 1024 + col] =
                (_Float16)((acc[mf][nf][i] + bv) * qscale);
          }
      } else if (col < 1088) {  // k_sum
        int ck = col - 1024;
#pragma unroll
        for (int mf = 0; mf < 4; ++mf)
#pragma unroll
          for (int i = 0; i < 4; ++i) {
            int row = m0 + mf * 16 + q4 * 4 + i;
            kbo[(size_t)row * 64 + ck] = (_Float16)(acc[mf][nf][i] + bv);
          }
      } else {  // v_sum, transposed: vtb[(b*64+d)*S + s]
        int d = col - 1088;
#pragma unroll
        for (int mf = 0; mf < 4; ++mf) {
          int row0 = m0 + mf * 16 + q4 * 4;
          int bb = row0 >> 11, sps = row0 & 2047;
          halfx4 o;
#pragma unroll
          for (int i = 0; i < 4; ++i) o[i] = (_Float16)(acc[mf][nf][i] + bv);
          *(halfx4*)&vto[((size_t)((bb << 6) + d)) * S_LEN + sps] = o;
        }
      }
    }
  }
}

// ---------------- flash v12: XCD-dispatch-aware chunk pairing --------------
// Block = 8 consecutive s-rows (one chunk), 8 waves, 1 wave = 1 full s-row.
// Per 128-t staged tile: 16 QK MFMA -> batched softmax (31-fmax tree, 32
// exp2, single defer-check) -> 16 PV MFMA. P reader-linear in LDS.
// Dispatch model (confirmed r4/r5: T = n_s*4.86 + (17-2n_s)*3.05, measured
// 50.6 = predicted pair(1,16) path): blocks (i, i+256) co-resident.
__global__ __launch_bounds__(512, 4) void flash_attn12(
    const _Float16* __restrict__ Qb, const _Float16* __restrict__ kb,
    const _Float16* __restrict__ vtb, _Float16* __restrict__ aob) {
  __shared__ _Float16 Ks[128][64];   // 16 KB  K tile [t][d], XOR-swizzled
  __shared__ _Float16 Vt[64][128];   // 16 KB  V^T tile [d][t], per-64-half swz
  __shared__ _Float16 Ps[8][2048];   // 32 KB  per-wave P, reader-linear
  int tid = threadIdx.x;
  int lane = tid & 63, w = tid >> 6, ln = lane & 15, q4 = lane >> 4;
  int bx = (int)blockIdx.x;
  int lo = bx & 255;
  int b = lo & 1;                               // batch
  int crow = (bx >> 8) ? (255 - (lo >> 1)) : (lo >> 1);  // row-chunk
  int s0 = crow * 8;
  int s = s0 + w;
  size_t bS = (size_t)b * S_LEN;

  // K staging: wave w covers t-rows w*16..+15; lane: row += lane>>3, grp^row
  int rr = lane >> 3, ggk = ((lane & 7) ^ rr) * 8;
  const _Float16* kgp = kb + (bS + w * 16 + rr) * 64 + ggk;
  // V staging: wave w covers d-rows w*8..+7; lane: row += lane>>4,
  // t-col = half*64 + (vg ^ (row&7))*8, vg = lane&7, half = (lane>>3)&1
  int vr = lane >> 4;
  int vhalf = (lane >> 3) & 1, vg = lane & 7;
  const _Float16* vgp[2];
#pragma unroll
  for (int j = 0; j < 2; ++j) {
    int row = w * 8 + 4 * j + vr;
    vgp[j] = vtb + ((size_t)b * 64 + row) * S_LEN + vhalf * 64 +
             ((vg ^ (row & 7)) * 8);
  }
  int swk0 = (q4 ^ (ln & 7)) * 8;
  int swk1 = ((q4 + 4) ^ (ln & 7)) * 8;
  _Float16* Pw = &Ps[w][0];
  // P write (halfx4): half-idx = (tq*8+tf*2)*128 + pwbase
  int pwbase = (q4 >> 1) * 128 + ln * 8 + (q4 & 1) * 4;
  // P read (halfx8): half-idx = kc*512 + prbase  (lane-linear)
  int prbase = q4 * 128 + ln * 8;

  const _Float16* qp = Qb + (bS + s) * DIM + ln * 64 + q4 * 8;
  halfx8 bq0 = *(const halfx8*)qp, bq1 = *(const halfx8*)(qp + 32);

  float m_run = -1e30f, l_run = 0.f;
  floatx4 oacc[4] = {};
  int nt = (crow >> 4) + 1;

  for (int it = 0; it < nt; ++it) {
    int t0 = it << 7;
    __syncthreads();
    gll16(kgp + (size_t)t0 * 64, &Ks[w * 16][0]);
    gll16(kgp + (size_t)(t0 + 8) * 64, &Ks[w * 16 + 8][0]);
    gll16(vgp[0] + t0, &Vt[w * 8][0]);
    gll16(vgp[1] + t0, &Vt[w * 8 + 4][0]);
    __syncthreads();

    // S^T = K Q^T (log2 domain): frag (tq,tf) rows t = t0+tq*64+tf*16+ln
    floatx4 sf[2][4];
    __builtin_amdgcn_s_setprio(1);
#pragma unroll
    for (int tq = 0; tq < 2; ++tq)
#pragma unroll
      for (int tf = 0; tf < 4; ++tf) {
        halfx8 ak0 = *(const halfx8*)&Ks[tq * 64 + tf * 16 + ln][swk0];
        halfx8 ak1 = *(const halfx8*)&Ks[tq * 64 + tf * 16 + ln][swk1];
        floatx4 z = {};
        z = mfma16(ak0, bq0, z);
        sf[tq][tf] = mfma16(ak1, bq1, z);
      }
    __builtin_amdgcn_s_setprio(0);
    if (it == nt - 1) {  // causal mask (block-uniform: only final tile)
#pragma unroll
      for (int tq = 0; tq < 2; ++tq)
#pragma unroll
        for (int tf = 0; tf < 4; ++tf)
#pragma unroll
          for (int i = 0; i < 4; ++i) {
            int t = t0 + tq * 64 + tf * 16 + q4 * 4 + i;
            if (t > s) sf[tq][tf][i] = -1e30f;
          }
    }
    // batched max over all 32 values
    float tm = -1e30f;
#pragma unroll
    for (int tq = 0; tq < 2; ++tq)
#pragma unroll
      for (int tf = 0; tf < 4; ++tf)
        tm = fmaxf(tm, fmaxf(fmaxf(sf[tq][tf][0], sf[tq][tf][1]),
                             fmaxf(sf[tq][tf][2], sf[tq][tf][3])));
    tm = fmaxf(tm, __shfl_xor(tm, 16));
    tm = fmaxf(tm, __shfl_xor(tm, 32));
    // defer-rescale (T13): skip O/l rescale while max drift <= 8 (log2)
    if (!__all(tm <= m_run + 8.f)) {
      float mn = fmaxf(m_run, tm);
      float alpha = exp2f(m_run - mn);
      m_run = mn;
      l_run *= alpha;
#pragma unroll
      for (int n2 = 0; n2 < 4; ++n2)
#pragma unroll
        for (int i = 0; i < 4; ++i) oacc[n2][i] *= alpha;
    }
    float rs = 0.f;
#pragma unroll
    for (int tq = 0; tq < 2; ++tq)
#pragma unroll
      for (int tf = 0; tf < 4; ++tf) {
        float p0 = exp2f(sf[tq][tf][0] - m_run);
        float p1 = exp2f(sf[tq][tf][1] - m_run);
        float p2 = exp2f(sf[tq][tf][2] - m_run);
        float p3 = exp2f(sf[tq][tf][3] - m_run);
        rs += (p0 + p1) + (p2 + p3);
        halfx4 pk;
        pk[0] = (_Float16)p0; pk[1] = (_Float16)p1;
        pk[2] = (_Float16)p2; pk[3] = (_Float16)p3;
        *(halfx4*)&Pw[(tq * 8 + tf * 2) * 128 + pwbase] = pk;
      }
    rs += __shfl_xor(rs, 16);
    rs += __shfl_xor(rs, 32);
    l_run += rs;
    // PV: O^T += V^T x P over 4 k-chunks of 32 t
    halfx8 bp[4];
#pragma unroll
    for (int kc = 0; kc < 4; ++kc)
      bp[kc] = *(const halfx8*)&Pw[kc * 512 + prbase];
    __builtin_amdgcn_s_setprio(1);
#pragma unroll
    for (int kc = 0; kc < 4; ++kc) {
      int half = (kc >> 1) * 64;
      int sw = ((q4 + 4 * (kc & 1)) ^ (ln & 7)) * 8;
#pragma unroll
      for (int n2 = 0; n2 < 4; ++n2) {
        halfx8 av = *(const halfx8*)&Vt[n2 * 16 + ln][half + sw];
        oacc[n2] = mfma16(av, bp[kc], oacc[n2]);
      }
    }
    __builtin_amdgcn_s_setprio(0);
  }
  // epilogue: O^T frag n2: h=ln, d=n2*16+q4*4+i (wave owns the full row)
  float inv = 1.0f / l_run;
#pragma unroll
  for (int n2 = 0; n2 < 4; ++n2) {
    halfx4 o;
#pragma unroll
    for (int i = 0; i < 4; ++i) o[i] = (_Float16)(oacc[n2][i] * inv);
    *(halfx4*)(aob + (bS + s) * DIM + ln * 64 + n2 * 16 + q4 * 4) = o;
  }
}

extern "C" void kernel_launch(void* const* d_in, const int* in_sizes, int n_in,
                              void* d_out, int out_size, void* d_ws,
                              size_t ws_size, hipStream_t stream) {
  const float* x    = (const float*)d_in[0];
  const float* wqkv = (const float*)d_in[1];
  const float* bqkv = (const float*)d_in[2];
  const float* wout = (const float*)d_in[3];
  const float* bout = (const float*)d_in[4];
  float* out = (float*)d_out;
  char* ws = (char*)d_ws;
  _Float16* xb    = (_Float16*)(ws);                               // 8 MB
  _Float16* qb    = (_Float16*)(ws + (8u << 20));                  // 8 MB
  _Float16* aob   = (_Float16*)(ws + (16u << 20));                 // 8 MB
  _Float16* kb    = (_Float16*)(ws + (24u << 20));                 // 512 KB
  _Float16* vtb   = (_Float16*)(ws + (24u << 20) + (512u << 10));  // 512 KB
  _Float16* wcomb = (_Float16*)(ws + (25u << 20));                 // 2.25 MB
  _Float16* woutb = (_Float16*)(ws + (27u << 20) + (512u << 10));  // 2 MB
  float*    bcomb = (float*)(ws + (29u << 20) + (512u << 10));     // 4.6 KB

  hipLaunchKernelGGL(prep_all, dim3(6656), dim3(256), 0, stream,
                     x, wqkv, bqkv, wout, xb, wcomb, woutb, bcomb);
  hipLaunchKernelGGL((gemm_t4<0>), dim3(64, 9), dim3(256), 0, stream,
                     xb, wcomb, bcomb, (void*)qb, kb, vtb);
  hipLaunchKernelGGL(flash_attn12, dim3(512), dim3(512), 0, stream,
                     qb, kb, vtb, aob);
  hipLaunchKernelGGL((gemm_t4<1>), dim3(64, 8), dim3(256), 0, stream,
                     aob, woutb, bout, (void*)out, nullptr, nullptr);
}

// Round 9
// 165.854 us; speedup vs baseline: 1.0367x; 1.0004x over previous
//
#include <hip/hip_runtime.h>

// Problem: B=2, S=2048, D=1024, H=16, HD=64. fp32 in/out.
// Pipeline exploits head-summed K/V: k_sum = x @ (sum_h Wk_h)^T + sum_h bk_h.
//  1. prep_all:    x, Wout -> f16; wcomb = [Wq; Wred] f16 (1152x1024); bcomb
//  2. gemm_t4<0>:  [Q*scale | k_sum | v_sum^T-permuted] = x @ wcomb^T + bcomb
//  3. flash_attn13: register-only P handoff. V stored sigma-permuted per
//                  128-block (p=(2tq+a)*32+q4*8+tf*2+b for t=tq*64+tf*16+
//                  q4*4+2a+b), so the PV B-fragment is built with 16
//                  lane-local v_cvt_pkrtz -- no P LDS round trip at all.
//  4. gemm_t4<1>:  out = ao @ Wout^T + bout   (4096x1024x1024) -> f32

#define S_LEN 2048
#define DIM 1024

using floatx4 = __attribute__((ext_vector_type(4))) float;
using halfx8  = __attribute__((ext_vector_type(8))) _Float16;
using halfx4  = __attribute__((ext_vector_type(4))) _Float16;
using halfx2  = __attribute__((ext_vector_type(2))) _Float16;
using fp16x2  = __attribute__((ext_vector_type(2))) __fp16;  // cvt_pkrtz ret

__device__ __forceinline__ floatx4 mfma16(halfx8 a, halfx8 b, floatx4 c) {
  return __builtin_amdgcn_mfma_f32_16x16x32_f16(a, b, c, 0, 0, 0);
}

// async global->LDS, 16B per lane; lds dst is wave-uniform base + lane*16
__device__ __forceinline__ void gll16(const void* g, void* l) {
  __builtin_amdgcn_global_load_lds(
      (const __attribute__((address_space(1))) void*)g,
      (__attribute__((address_space(3))) void*)l, 16, 0, 0);
}

// ---------------- prep: conversions + combined weights ----------------
__global__ __launch_bounds__(256) void prep_all(
    const float* __restrict__ x, const float* __restrict__ wqkv,
    const float* __restrict__ bqkv, const float* __restrict__ wout,
    _Float16* __restrict__ xb, _Float16* __restrict__ wcomb,
    _Float16* __restrict__ woutb, float* __restrict__ bcomb) {
  int bx = blockIdx.x;
  if (bx < 6144) {
    size_t i4 = ((size_t)bx * 256 + threadIdx.x) * 4;
    const float* src;
    _Float16* dst;
    size_t off;
    if (i4 < 4194304) { src = x; dst = xb; off = i4; }
    else if (i4 < 5242880) { src = wqkv; dst = wcomb; off = i4 - 4194304; }
    else { src = wout; dst = woutb; off = i4 - 5242880; }
    float4 v = *(const float4*)(src + off);
    halfx4 o;
    o[0] = (_Float16)v.x; o[1] = (_Float16)v.y;
    o[2] = (_Float16)v.z; o[3] = (_Float16)v.w;
    *(halfx4*)(dst + off) = o;
  } else {
    int gid = (bx - 6144) * 256 + threadIdx.x;  // 131072 threads
    int c = gid >> 10, j = gid & 1023;
    int row0 = (c < 64) ? (1024 + c) : (2048 + c - 64);
    float s = 0.f;
#pragma unroll
    for (int h = 0; h < 16; ++h) s += wqkv[(size_t)(row0 + h * 64) * 1024 + j];
    wcomb[(size_t)1024 * 1024 + gid] = (_Float16)s;
    if (gid < 1024) bcomb[gid] = bqkv[gid];
    if (gid < 128) {
      int b0 = (gid < 64) ? (1024 + gid) : (2048 + gid - 64);
      float sb = 0.f;
#pragma unroll
      for (int h = 0; h < 16; ++h) sb += bqkv[b0 + h * 64];
      bcomb[1024 + gid] = sb;
    }
  }
}

// ---- gemm_t4: 64M x 128N tile, BK=64, single-buffer, 2 barriers/step ----
// Wave w owns cols w*32 (4 m-frags x 2 n-frags). Staging per wave/K-step:
// A rows w*16..+15 (2 gll16), W rows w*32..+31 (4 gll16); XOR col-group
// swizzle (row r group g at g^(r&7)). LDS 24 KB -> high co-residency.
// MODE 0: N=1152 fused epilogue -> qb (*scale), kb, vtb (V^T, sigma-permuted
// per 128-s-block: p=(2tq+a)*32+q4*8+tf*2+b). MODE 1: f32 out.
template <int MODE>
__global__ __launch_bounds__(256, 3) void gemm_t4(
    const _Float16* __restrict__ A, const _Float16* __restrict__ W,
    const float* __restrict__ bias, void* __restrict__ Cv,
    _Float16* __restrict__ kbo, _Float16* __restrict__ vto) {
  const int K = 1024;
  __shared__ _Float16 As[64][64];   // 8 KB
  __shared__ _Float16 Ws[128][64];  // 16 KB
  int tid = threadIdx.x;
  int lane = tid & 63, w = tid >> 6, ln = lane & 15, q4 = lane >> 4;
  int m0 = blockIdx.x * 64, n0 = blockIdx.y * 128;
  int rr = lane >> 3, gg = ((lane & 7) ^ rr) * 8;  // staging lane row/col
  const _Float16* agp = A + (size_t)(m0 + w * 16 + rr) * K + gg;
  const _Float16* wgp = W + (size_t)(n0 + w * 32 + rr) * K + gg;
  floatx4 acc[4][2] = {};
  for (int kt = 0; kt < K; kt += 64) {
    __syncthreads();  // readers done with previous tile
#pragma unroll
    for (int j = 0; j < 2; ++j)
      gll16(agp + (size_t)(8 * j) * K + kt, &As[w * 16 + 8 * j][0]);
#pragma unroll
    for (int j = 0; j < 4; ++j)
      gll16(wgp + (size_t)(8 * j) * K + kt, &Ws[w * 32 + 8 * j][0]);
    __syncthreads();  // staging visible
#pragma unroll
    for (int kh = 0; kh < 2; ++kh) {
      int sw = ((q4 + 4 * kh) ^ (ln & 7)) * 8;
      halfx8 bf[2];
#pragma unroll
      for (int nf = 0; nf < 2; ++nf)
        bf[nf] = *(const halfx8*)&Ws[w * 32 + nf * 16 + ln][sw];
#pragma unroll
      for (int mf = 0; mf < 4; ++mf) {
        halfx8 af = *(const halfx8*)&As[mf * 16 + ln][sw];
#pragma unroll
        for (int nf = 0; nf < 2; ++nf)
          acc[mf][nf] = mfma16(af, bf[nf], acc[mf][nf]);
      }
    }
  }
  const float qscale = 0.18033688011112042f;  // (1/sqrt(64)) * log2(e)
#pragma unroll
  for (int nf = 0; nf < 2; ++nf) {
    int col = n0 + w * 32 + nf * 16 + ln;
    float bv = bias[col];
    if constexpr (MODE == 1) {
#pragma unroll
      for (int mf = 0; mf < 4; ++mf)
#pragma unroll
        for (int i = 0; i < 4; ++i) {
          int row = m0 + mf * 16 + q4 * 4 + i;
          ((float*)Cv)[(size_t)row * 1024 + col] = acc[mf][nf][i] + bv;
        }
    } else {
      if (col < 1024) {  // Q, pre-scaled for log2-domain softmax
#pragma unroll
        for (int mf = 0; mf < 4; ++mf)
#pragma unroll
          for (int i = 0; i < 4; ++i) {
            int row = m0 + mf * 16 + q4 * 4 + i;
            ((_Float16*)Cv)[(size_t)row * 1024 + col] =
                (_Float16)((acc[mf][nf][i] + bv) * qscale);
          }
      } else if (col < 1088) {  // k_sum
        int ck = col - 1024;
#pragma unroll
        for (int mf = 0; mf < 4; ++mf)
#pragma unroll
          for (int i = 0; i < 4; ++i) {
            int row = m0 + mf * 16 + q4 * 4 + i;
            kbo[(size_t)row * 64 + ck] = (_Float16)(acc[mf][nf][i] + bv);
          }
      } else {  // v_sum, transposed + sigma-permuted within each 128-s block
        int d = col - 1088;
#pragma unroll
        for (int mf = 0; mf < 4; ++mf) {
          int row0 = m0 + mf * 16 + q4 * 4;  // 4 consecutive s, 4-aligned
          int bb = row0 >> 11, sps = row0 & 2047;
          int blk = sps & ~127, tl = sps & 127;
          // p(t): t=tq*64+tf*16+q4l*4+rem -> p=(2tq+(rem>>1))*32+q4l*8+tf*2+(rem&1)
          int p0 = (tl >> 6) * 64 + ((tl >> 2) & 3) * 8 + ((tl >> 4) & 3) * 2;
          _Float16* basep =
              &vto[((size_t)((bb << 6) + d)) * S_LEN + blk];
          halfx2 lo, hi;
          lo[0] = (_Float16)(acc[mf][nf][0] + bv);
          lo[1] = (_Float16)(acc[mf][nf][1] + bv);
          hi[0] = (_Float16)(acc[mf][nf][2] + bv);
          hi[1] = (_Float16)(acc[mf][nf][3] + bv);
          *(halfx2*)&basep[p0] = lo;        // rem 0,1 -> a=0
          *(halfx2*)&basep[p0 + 32] = hi;   // rem 2,3 -> a=1
        }
      }
    }
  }
}

// ------- flash v13: register-only P handoff (sigma-permuted V) -------------
// Block = 8 consecutive s-rows (one chunk), 8 waves, 1 wave = 1 full s-row.
// Per 128-t staged tile: 16 QK MFMA -> batched softmax -> bp built with 16
// lane-local v_cvt_pkrtz (sigma makes the PV B-frag lane-local; verified
// t=5 / t=77 element round-trips) -> 16 PV MFMA. No P LDS, LDS 32 KB.
// Dispatch pairing (r4/r5-validated model): blocks (i, i+256) co-resident;
// mapping gives every pair 17 staging units.
__global__ __launch_bounds__(512, 4) void flash_attn13(
    const _Float16* __restrict__ Qb, const _Float16* __restrict__ kb,
    const _Float16* __restrict__ vtb, _Float16* __restrict__ aob) {
  __shared__ _Float16 Ks[128][64];   // 16 KB  K tile [t][d], XOR-swizzled
  __shared__ _Float16 Vt[64][128];   // 16 KB  V^T tile [d][p], per-64-half swz
  int tid = threadIdx.x;
  int lane = tid & 63, w = tid >> 6, ln = lane & 15, q4 = lane >> 4;
  int bx = (int)blockIdx.x;
  int lo = bx & 255;
  int b = lo & 1;                               // batch
  int crow = (bx >> 8) ? (255 - (lo >> 1)) : (lo >> 1);  // row-chunk
  int s0 = crow * 8;
  int s = s0 + w;
  size_t bS = (size_t)b * S_LEN;

  // K staging: wave w covers t-rows w*16..+15; lane: row += lane>>3, grp^row
  int rr = lane >> 3, ggk = ((lane & 7) ^ rr) * 8;
  const _Float16* kgp = kb + (bS + w * 16 + rr) * 64 + ggk;
  // V staging: wave w covers d-rows w*8..+7; lane: row += lane>>4,
  // p-col = half*64 + (vg ^ (row&7))*8, vg = lane&7, half = (lane>>3)&1
  int vr = lane >> 4;
  int vhalf = (lane >> 3) & 1, vg = lane & 7;
  const _Float16* vgp[2];
#pragma unroll
  for (int j = 0; j < 2; ++j) {
    int row = w * 8 + 4 * j + vr;
    vgp[j] = vtb + ((size_t)b * 64 + row) * S_LEN + vhalf * 64 +
             ((vg ^ (row & 7)) * 8);
  }
  int swk0 = (q4 ^ (ln & 7)) * 8;
  int swk1 = ((q4 + 4) ^ (ln & 7)) * 8;

  const _Float16* qp = Qb + (bS + s) * DIM + ln * 64 + q4 * 8;
  halfx8 bq0 = *(const halfx8*)qp, bq1 = *(const halfx8*)(qp + 32);

  float m_run = -1e30f, l_run = 0.f;
  floatx4 oacc[4] = {};
  int nt = (crow >> 4) + 1;

  for (int it = 0; it < nt; ++it) {
    int t0 = it << 7;
    __syncthreads();
    gll16(kgp + (size_t)t0 * 64, &Ks[w * 16][0]);
    gll16(kgp + (size_t)(t0 + 8) * 64, &Ks[w * 16 + 8][0]);
    gll16(vgp[0] + t0, &Vt[w * 8][0]);
    gll16(vgp[1] + t0, &Vt[w * 8 + 4][0]);
    __syncthreads();

    // S^T = K Q^T (log2 domain): frag (tq,tf) rows t = t0+tq*64+tf*16+ln
    floatx4 sf[2][4];
    __builtin_amdgcn_s_setprio(1);
#pragma unroll
    for (int tq = 0; tq < 2; ++tq)
#pragma unroll
      for (int tf = 0; tf < 4; ++tf) {
        halfx8 ak0 = *(const halfx8*)&Ks[tq * 64 + tf * 16 + ln][swk0];
        halfx8 ak1 = *(const halfx8*)&Ks[tq * 64 + tf * 16 + ln][swk1];
        floatx4 z = {};
        z = mfma16(ak0, bq0, z);
        sf[tq][tf] = mfma16(ak1, bq1, z);
      }
    __builtin_amdgcn_s_setprio(0);
    if (it == nt - 1) {  // causal mask (block-uniform: only final tile)
#pragma unroll
      for (int tq = 0; tq < 2; ++tq)
#pragma unroll
        for (int tf = 0; tf < 4; ++tf)
#pragma unroll
          for (int i = 0; i < 4; ++i) {
            int t = t0 + tq * 64 + tf * 16 + q4 * 4 + i;
            if (t > s) sf[tq][tf][i] = -1e30f;
          }
    }
    // batched max over all 32 values
    float tm = -1e30f;
#pragma unroll
    for (int tq = 0; tq < 2; ++tq)
#pragma unroll
      for (int tf = 0; tf < 4; ++tf)
        tm = fmaxf(tm, fmaxf(fmaxf(sf[tq][tf][0], sf[tq][tf][1]),
                             fmaxf(sf[tq][tf][2], sf[tq][tf][3])));
    tm = fmaxf(tm, __shfl_xor(tm, 16));
    tm = fmaxf(tm, __shfl_xor(tm, 32));
    // defer-rescale (T13): skip O/l rescale while max drift <= 8 (log2)
    if (!__all(tm <= m_run + 8.f)) {
      float mn = fmaxf(m_run, tm);
      float alpha = exp2f(m_run - mn);
      m_run = mn;
      l_run *= alpha;
#pragma unroll
      for (int n2 = 0; n2 < 4; ++n2)
#pragma unroll
        for (int i = 0; i < 4; ++i) oacc[n2][i] *= alpha;
    }
    // exp2 + lane-local PV B-frag build: bp[2tq+a] word tf = pkrtz(p2a,p2a+1)
    float rs = 0.f;
    unsigned bpw[4][4];
#pragma unroll
    for (int tq = 0; tq < 2; ++tq)
#pragma unroll
      for (int tf = 0; tf < 4; ++tf) {
        float p0 = exp2f(sf[tq][tf][0] - m_run);
        float p1 = exp2f(sf[tq][tf][1] - m_run);
        float p2 = exp2f(sf[tq][tf][2] - m_run);
        float p3 = exp2f(sf[tq][tf][3] - m_run);
        rs += (p0 + p1) + (p2 + p3);
        union { fp16x2 h; unsigned u; } c0, c1;
        c0.h = __builtin_amdgcn_cvt_pkrtz(p0, p1);
        c1.h = __builtin_amdgcn_cvt_pkrtz(p2, p3);
        bpw[2 * tq][tf] = c0.u;
        bpw[2 * tq + 1][tf] = c1.u;
      }
    rs += __shfl_xor(rs, 16);
    rs += __shfl_xor(rs, 32);
    l_run += rs;
    // PV: O^T += V^T x P over 4 k-chunks of 32 t (sigma-order, reg operand)
    __builtin_amdgcn_s_setprio(1);
#pragma unroll
    for (int kc = 0; kc < 4; ++kc) {
      union { unsigned u[4]; halfx8 v; } bpu;
#pragma unroll
      for (int ww = 0; ww < 4; ++ww) bpu.u[ww] = bpw[kc][ww];
      int half = (kc >> 1) * 64;
      int sw = ((q4 + 4 * (kc & 1)) ^ (ln & 7)) * 8;
#pragma unroll
      for (int n2 = 0; n2 < 4; ++n2) {
        halfx8 av = *(const halfx8*)&Vt[n2 * 16 + ln][half + sw];
        oacc[n2] = mfma16(av, bpu.v, oacc[n2]);
      }
    }
    __builtin_amdgcn_s_setprio(0);
  }
  // epilogue: O^T frag n2: h=ln, d=n2*16+q4*4+i (wave owns the full row)
  float inv = 1.0f / l_run;
#pragma unroll
  for (int n2 = 0; n2 < 4; ++n2) {
    halfx4 o;
#pragma unroll
    for (int i = 0; i < 4; ++i) o[i] = (_Float16)(oacc[n2][i] * inv);
    *(halfx4*)(aob + (bS + s) * DIM + ln * 64 + n2 * 16 + q4 * 4) = o;
  }
}

extern "C" void kernel_launch(void* const* d_in, const int* in_sizes, int n_in,
                              void* d_out, int out_size, void* d_ws,
                              size_t ws_size, hipStream_t stream) {
  const float* x    = (const float*)d_in[0];
  const float* wqkv = (const float*)d_in[1];
  const float* bqkv = (const float*)d_in[2];
  const float* wout = (const float*)d_in[3];
  const float* bout = (const float*)d_in[4];
  float* out = (float*)d_out;
  char* ws = (char*)d_ws;
  _Float16* xb    = (_Float16*)(ws);                               // 8 MB
  _Float16* qb    = (_Float16*)(ws + (8u << 20));                  // 8 MB
  _Float16* aob   = (_Float16*)(ws + (16u << 20));                 // 8 MB
  _Float16* kb    = (_Float16*)(ws + (24u << 20));                 // 512 KB
  _Float16* vtb   = (_Float16*)(ws + (24u << 20) + (512u << 10));  // 512 KB
  _Float16* wcomb = (_Float16*)(ws + (25u << 20));                 // 2.25 MB
  _Float16* woutb = (_Float16*)(ws + (27u << 20) + (512u << 10));  // 2 MB
  float*    bcomb = (float*)(ws + (29u << 20) + (512u << 10));     // 4.6 KB

  hipLaunchKernelGGL(prep_all, dim3(6656), dim3(256), 0, stream,
                     x, wqkv, bqkv, wout, xb, wcomb, woutb, bcomb);
  hipLaunchKernelGGL((gemm_t4<0>), dim3(64, 9), dim3(256), 0, stream,
                     xb, wcomb, bcomb, (void*)qb, kb, vtb);
  hipLaunchKernelGGL(flash_attn13, dim3(512), dim3(512), 0, stream,
                     qb, kb, vtb, aob);
  hipLaunchKernelGGL((gemm_t4<1>), dim3(64, 8), dim3(256), 0, stream,
                     aob, woutb, bout, (void*)out, nullptr, nullptr);
}

// Round 10
// 162.936 us; speedup vs baseline: 1.0552x; 1.0179x over previous
//
#include <hip/hip_runtime.h>

// Problem: B=2, S=2048, D=1024, H=16, HD=64. fp32 in/out.
// Pipeline exploits head-summed K/V: k_sum = x @ (sum_h Wk_h)^T + sum_h bk_h.
//  1. prep_all:    x, Wout -> f16; wcomb = [Wq; Wred] f16 (1152x1024); bcomb
//  2. gemm_t4<0>:  [Q*scale | k_sum | v_sum^T-permuted] = x @ wcomb^T + bcomb
//  3. flash_attn14: v13 (register-only P handoff, sigma-permuted V) + K/V
//                  DOUBLE-BUFFERED staging: stage(it+1) issued before
//                  compute(it), ONE barrier per tile. Hides the gll16 drain
//                  that dominated the solo-block unit cost (7300 cyc/unit vs
//                  ~1100 compute). LDS 64 KB, 2 blocks/CU.
//  4. gemm_t4<1>:  out = ao @ Wout^T + bout   (4096x1024x1024) -> f32

#define S_LEN 2048
#define DIM 1024

using floatx4 = __attribute__((ext_vector_type(4))) float;
using halfx8  = __attribute__((ext_vector_type(8))) _Float16;
using halfx4  = __attribute__((ext_vector_type(4))) _Float16;
using halfx2  = __attribute__((ext_vector_type(2))) _Float16;
using fp16x2  = __attribute__((ext_vector_type(2))) __fp16;  // cvt_pkrtz ret

__device__ __forceinline__ floatx4 mfma16(halfx8 a, halfx8 b, floatx4 c) {
  return __builtin_amdgcn_mfma_f32_16x16x32_f16(a, b, c, 0, 0, 0);
}

// async global->LDS, 16B per lane; lds dst is wave-uniform base + lane*16
__device__ __forceinline__ void gll16(const void* g, void* l) {
  __builtin_amdgcn_global_load_lds(
      (const __attribute__((address_space(1))) void*)g,
      (__attribute__((address_space(3))) void*)l, 16, 0, 0);
}

// ---------------- prep: conversions + combined weights ----------------
__global__ __launch_bounds__(256) void prep_all(
    const float* __restrict__ x, const float* __restrict__ wqkv,
    const float* __restrict__ bqkv, const float* __restrict__ wout,
    _Float16* __restrict__ xb, _Float16* __restrict__ wcomb,
    _Float16* __restrict__ woutb, float* __restrict__ bcomb) {
  int bx = blockIdx.x;
  if (bx < 6144) {
    size_t i4 = ((size_t)bx * 256 + threadIdx.x) * 4;
    const float* src;
    _Float16* dst;
    size_t off;
    if (i4 < 4194304) { src = x; dst = xb; off = i4; }
    else if (i4 < 5242880) { src = wqkv; dst = wcomb; off = i4 - 4194304; }
    else { src = wout; dst = woutb; off = i4 - 5242880; }
    float4 v = *(const float4*)(src + off);
    halfx4 o;
    o[0] = (_Float16)v.x; o[1] = (_Float16)v.y;
    o[2] = (_Float16)v.z; o[3] = (_Float16)v.w;
    *(halfx4*)(dst + off) = o;
  } else {
    int gid = (bx - 6144) * 256 + threadIdx.x;  // 131072 threads
    int c = gid >> 10, j = gid & 1023;
    int row0 = (c < 64) ? (1024 + c) : (2048 + c - 64);
    float s = 0.f;
#pragma unroll
    for (int h = 0; h < 16; ++h) s += wqkv[(size_t)(row0 + h * 64) * 1024 + j];
    wcomb[(size_t)1024 * 1024 + gid] = (_Float16)s;
    if (gid < 1024) bcomb[gid] = bqkv[gid];
    if (gid < 128) {
      int b0 = (gid < 64) ? (1024 + gid) : (2048 + gid - 64);
      float sb = 0.f;
#pragma unroll
      for (int h = 0; h < 16; ++h) sb += bqkv[b0 + h * 64];
      bcomb[1024 + gid] = sb;
    }
  }
}

// ---- gemm_t4: 64M x 128N tile, BK=64, single-buffer, 2 barriers/step ----
// Wave w owns cols w*32 (4 m-frags x 2 n-frags). Staging per wave/K-step:
// A rows w*16..+15 (2 gll16), W rows w*32..+31 (4 gll16); XOR col-group
// swizzle (row r group g at g^(r&7)). LDS 24 KB -> high co-residency.
// MODE 0: N=1152 fused epilogue -> qb (*scale), kb, vtb (V^T, sigma-permuted
// per 128-s-block: p=(2tq+a)*32+q4*8+tf*2+b). MODE 1: f32 out.
template <int MODE>
__global__ __launch_bounds__(256, 3) void gemm_t4(
    const _Float16* __restrict__ A, const _Float16* __restrict__ W,
    const float* __restrict__ bias, void* __restrict__ Cv,
    _Float16* __restrict__ kbo, _Float16* __restrict__ vto) {
  const int K = 1024;
  __shared__ _Float16 As[64][64];   // 8 KB
  __shared__ _Float16 Ws[128][64];  // 16 KB
  int tid = threadIdx.x;
  int lane = tid & 63, w = tid >> 6, ln = lane & 15, q4 = lane >> 4;
  int m0 = blockIdx.x * 64, n0 = blockIdx.y * 128;
  int rr = lane >> 3, gg = ((lane & 7) ^ rr) * 8;  // staging lane row/col
  const _Float16* agp = A + (size_t)(m0 + w * 16 + rr) * K + gg;
  const _Float16* wgp = W + (size_t)(n0 + w * 32 + rr) * K + gg;
  floatx4 acc[4][2] = {};
  for (int kt = 0; kt < K; kt += 64) {
    __syncthreads();  // readers done with previous tile
#pragma unroll
    for (int j = 0; j < 2; ++j)
      gll16(agp + (size_t)(8 * j) * K + kt, &As[w * 16 + 8 * j][0]);
#pragma unroll
    for (int j = 0; j < 4; ++j)
      gll16(wgp + (size_t)(8 * j) * K + kt, &Ws[w * 32 + 8 * j][0]);
    __syncthreads();  // staging visible
#pragma unroll
    for (int kh = 0; kh < 2; ++kh) {
      int sw = ((q4 + 4 * kh) ^ (ln & 7)) * 8;
      halfx8 bf[2];
#pragma unroll
      for (int nf = 0; nf < 2; ++nf)
        bf[nf] = *(const halfx8*)&Ws[w * 32 + nf * 16 + ln][sw];
#pragma unroll
      for (int mf = 0; mf < 4; ++mf) {
        halfx8 af = *(const halfx8*)&As[mf * 16 + ln][sw];
#pragma unroll
        for (int nf = 0; nf < 2; ++nf)
          acc[mf][nf] = mfma16(af, bf[nf], acc[mf][nf]);
      }
    }
  }
  const float qscale = 0.18033688011112042f;  // (1/sqrt(64)) * log2(e)
#pragma unroll
  for (int nf = 0; nf < 2; ++nf) {
    int col = n0 + w * 32 + nf * 16 + ln;
    float bv = bias[col];
    if constexpr (MODE == 1) {
#pragma unroll
      for (int mf = 0; mf < 4; ++mf)
#pragma unroll
        for (int i = 0; i < 4; ++i) {
          int row = m0 + mf * 16 + q4 * 4 + i;
          ((float*)Cv)[(size_t)row * 1024 + col] = acc[mf][nf][i] + bv;
        }
    } else {
      if (col < 1024) {  // Q, pre-scaled for log2-domain softmax
#pragma unroll
        for (int mf = 0; mf < 4; ++mf)
#pragma unroll
          for (int i = 0; i < 4; ++i) {
            int row = m0 + mf * 16 + q4 * 4 + i;
            ((_Float16*)Cv)[(size_t)row * 1024 + col] =
                (_Float16)((acc[mf][nf][i] + bv) * qscale);
          }
      } else if (col < 1088) {  // k_sum
        int ck = col - 1024;
#pragma unroll
        for (int mf = 0; mf < 4; ++mf)
#pragma unroll
          for (int i = 0; i < 4; ++i) {
            int row = m0 + mf * 16 + q4 * 4 + i;
            kbo[(size_t)row * 64 + ck] = (_Float16)(acc[mf][nf][i] + bv);
          }
      } else {  // v_sum, transposed + sigma-permuted within each 128-s block
        int d = col - 1088;
#pragma unroll
        for (int mf = 0; mf < 4; ++mf) {
          int row0 = m0 + mf * 16 + q4 * 4;  // 4 consecutive s, 4-aligned
          int bb = row0 >> 11, sps = row0 & 2047;
          int blk = sps & ~127, tl = sps & 127;
          // p(t): t=tq*64+tf*16+q4l*4+rem -> p=(2tq+(rem>>1))*32+q4l*8+tf*2+(rem&1)
          int p0 = (tl >> 6) * 64 + ((tl >> 2) & 3) * 8 + ((tl >> 4) & 3) * 2;
          _Float16* basep =
              &vto[((size_t)((bb << 6) + d)) * S_LEN + blk];
          halfx2 lo, hi;
          lo[0] = (_Float16)(acc[mf][nf][0] + bv);
          lo[1] = (_Float16)(acc[mf][nf][1] + bv);
          hi[0] = (_Float16)(acc[mf][nf][2] + bv);
          hi[1] = (_Float16)(acc[mf][nf][3] + bv);
          *(halfx2*)&basep[p0] = lo;        // rem 0,1 -> a=0
          *(halfx2*)&basep[p0 + 32] = hi;   // rem 2,3 -> a=1
        }
      }
    }
  }
}

// ------- flash v14: v13 + double-buffered K/V staging (1 barrier/tile) -----
// Block = 8 consecutive s-rows (one chunk), 8 waves, 1 wave = 1 full s-row.
// Per 128-t tile: issue stage(it+1, nxt) -> 16 QK MFMA -> batched softmax ->
// 16 lane-local cvt_pkrtz (sigma-permuted V makes PV B-frag lane-local) ->
// 16 PV MFMA -> barrier (vmcnt drain covers the prefetch; also guards buffer
// reuse at it+2). Dispatch pairing (r4/r5 model): blocks (i,i+256)
// co-resident; mapping gives every pair 17 staging units.
__global__ __launch_bounds__(512, 4) void flash_attn14(
    const _Float16* __restrict__ Qb, const _Float16* __restrict__ kb,
    const _Float16* __restrict__ vtb, _Float16* __restrict__ aob) {
  __shared__ _Float16 Ks[2][128][64];   // 32 KB  K tiles, XOR-swizzled
  __shared__ _Float16 Vt[2][64][128];   // 32 KB  V^T tiles (sigma-permuted)
  int tid = threadIdx.x;
  int lane = tid & 63, w = tid >> 6, ln = lane & 15, q4 = lane >> 4;
  int bx = (int)blockIdx.x;
  int lo = bx & 255;
  int b = lo & 1;                               // batch
  int crow = (bx >> 8) ? (255 - (lo >> 1)) : (lo >> 1);  // row-chunk
  int s0 = crow * 8;
  int s = s0 + w;
  size_t bS = (size_t)b * S_LEN;

  // K staging: wave w covers t-rows w*16..+15; lane: row += lane>>3, grp^row
  int rr = lane >> 3, ggk = ((lane & 7) ^ rr) * 8;
  const _Float16* kgp = kb + (bS + w * 16 + rr) * 64 + ggk;
  // V staging: wave w covers d-rows w*8..+7; lane: row += lane>>4,
  // p-col = half*64 + (vg ^ (row&7))*8, vg = lane&7, half = (lane>>3)&1
  int vr = lane >> 4;
  int vhalf = (lane >> 3) & 1, vg = lane & 7;
  const _Float16* vgp[2];
#pragma unroll
  for (int j = 0; j < 2; ++j) {
    int row = w * 8 + 4 * j + vr;
    vgp[j] = vtb + ((size_t)b * 64 + row) * S_LEN + vhalf * 64 +
             ((vg ^ (row & 7)) * 8);
  }
  int swk0 = (q4 ^ (ln & 7)) * 8;
  int swk1 = ((q4 + 4) ^ (ln & 7)) * 8;

  const _Float16* qp = Qb + (bS + s) * DIM + ln * 64 + q4 * 8;
  halfx8 bq0 = *(const halfx8*)qp, bq1 = *(const halfx8*)(qp + 32);

  float m_run = -1e30f, l_run = 0.f;
  floatx4 oacc[4] = {};
  int nt = (crow >> 4) + 1;

  // prologue: stage tile 0 into buffer 0
  gll16(kgp, &Ks[0][w * 16][0]);
  gll16(kgp + (size_t)8 * 64, &Ks[0][w * 16 + 8][0]);
  gll16(vgp[0], &Vt[0][w * 8][0]);
  gll16(vgp[1], &Vt[0][w * 8 + 4][0]);
  __syncthreads();  // vmcnt drain: tile 0 visible

  for (int it = 0; it < nt; ++it) {
    int cur = it & 1, nxt = cur ^ 1;
    if (it + 1 < nt) {  // prefetch next tile; lands under this tile's compute
      int t1 = (it + 1) << 7;
      gll16(kgp + (size_t)t1 * 64, &Ks[nxt][w * 16][0]);
      gll16(kgp + (size_t)(t1 + 8) * 64, &Ks[nxt][w * 16 + 8][0]);
      gll16(vgp[0] + t1, &Vt[nxt][w * 8][0]);
      gll16(vgp[1] + t1, &Vt[nxt][w * 8 + 4][0]);
    }
    int t0 = it << 7;

    // S^T = K Q^T (log2 domain): frag (tq,tf) rows t = t0+tq*64+tf*16+ln
    floatx4 sf[2][4];
    __builtin_amdgcn_s_setprio(1);
#pragma unroll
    for (int tq = 0; tq < 2; ++tq)
#pragma unroll
      for (int tf = 0; tf < 4; ++tf) {
        halfx8 ak0 = *(const halfx8*)&Ks[cur][tq * 64 + tf * 16 + ln][swk0];
        halfx8 ak1 = *(const halfx8*)&Ks[cur][tq * 64 + tf * 16 + ln][swk1];
        floatx4 z = {};
        z = mfma16(ak0, bq0, z);
        sf[tq][tf] = mfma16(ak1, bq1, z);
      }
    __builtin_amdgcn_s_setprio(0);
    if (it == nt - 1) {  // causal mask (block-uniform: only final tile)
#pragma unroll
      for (int tq = 0; tq < 2; ++tq)
#pragma unroll
        for (int tf = 0; tf < 4; ++tf)
#pragma unroll
          for (int i = 0; i < 4; ++i) {
            int t = t0 + tq * 64 + tf * 16 + q4 * 4 + i;
            if (t > s) sf[tq][tf][i] = -1e30f;
          }
    }
    // batched max over all 32 values
    float tm = -1e30f;
#pragma unroll
    for (int tq = 0; tq < 2; ++tq)
#pragma unroll
      for (int tf = 0; tf < 4; ++tf)
        tm = fmaxf(tm, fmaxf(fmaxf(sf[tq][tf][0], sf[tq][tf][1]),
                             fmaxf(sf[tq][tf][2], sf[tq][tf][3])));
    tm = fmaxf(tm, __shfl_xor(tm, 16));
    tm = fmaxf(tm, __shfl_xor(tm, 32));
    // defer-rescale (T13): skip O/l rescale while max drift <= 8 (log2)
    if (!__all(tm <= m_run + 8.f)) {
      float mn = fmaxf(m_run, tm);
      float alpha = exp2f(m_run - mn);
      m_run = mn;
      l_run *= alpha;
#pragma unroll
      for (int n2 = 0; n2 < 4; ++n2)
#pragma unroll
        for (int i = 0; i < 4; ++i) oacc[n2][i] *= alpha;
    }
    // exp2 + lane-local PV B-frag build: bp[2tq+a] word tf = pkrtz(p2a,p2a+1)
    float rs = 0.f;
    unsigned bpw[4][4];
#pragma unroll
    for (int tq = 0; tq < 2; ++tq)
#pragma unroll
      for (int tf = 0; tf < 4; ++tf) {
        float p0 = exp2f(sf[tq][tf][0] - m_run);
        float p1 = exp2f(sf[tq][tf][1] - m_run);
        float p2 = exp2f(sf[tq][tf][2] - m_run);
        float p3 = exp2f(sf[tq][tf][3] - m_run);
        rs += (p0 + p1) + (p2 + p3);
        union { fp16x2 h; unsigned u; } c0, c1;
        c0.h = __builtin_amdgcn_cvt_pkrtz(p0, p1);
        c1.h = __builtin_amdgcn_cvt_pkrtz(p2, p3);
        bpw[2 * tq][tf] = c0.u;
        bpw[2 * tq + 1][tf] = c1.u;
      }
    rs += __shfl_xor(rs, 16);
    rs += __shfl_xor(rs, 32);
    l_run += rs;
    // PV: O^T += V^T x P over 4 k-chunks of 32 t (sigma-order, reg operand)
    __builtin_amdgcn_s_setprio(1);
#pragma unroll
    for (int kc = 0; kc < 4; ++kc) {
      union { unsigned u[4]; halfx8 v; } bpu;
#pragma unroll
      for (int ww = 0; ww < 4; ++ww) bpu.u[ww] = bpw[kc][ww];
      int half = (kc >> 1) * 64;
      int sw = ((q4 + 4 * (kc & 1)) ^ (ln & 7)) * 8;
#pragma unroll
      for (int n2 = 0; n2 < 4; ++n2) {
        halfx8 av = *(const halfx8*)&Vt[cur][n2 * 16 + ln][half + sw];
        oacc[n2] = mfma16(av, bpu.v, oacc[n2]);
      }
    }
    __builtin_amdgcn_s_setprio(0);
    // one barrier per tile: drains prefetch (landed under compute) and
    // guards buffer[cur] against overwrite by stage(it+2)
    __syncthreads();
  }
  // epilogue: O^T frag n2: h=ln, d=n2*16+q4*4+i (wave owns the full row)
  float inv = 1.0f / l_run;
#pragma unroll
  for (int n2 = 0; n2 < 4; ++n2) {
    halfx4 o;
#pragma unroll
    for (int i = 0; i < 4; ++i) o[i] = (_Float16)(oacc[n2][i] * inv);
    *(halfx4*)(aob + (bS + s) * DIM + ln * 64 + n2 * 16 + q4 * 4) = o;
  }
}

extern "C" void kernel_launch(void* const* d_in, const int* in_sizes, int n_in,
                              void* d_out, int out_size, void* d_ws,
                              size_t ws_size, hipStream_t stream) {
  const float* x    = (const float*)d_in[0];
  const float* wqkv = (const float*)d_in[1];
  const float* bqkv = (const float*)d_in[2];
  const float* wout = (const float*)d_in[3];
  const float* bout = (const float*)d_in[4];
  float* out = (float*)d_out;
  char* ws = (char*)d_ws;
  _Float16* xb    = (_Float16*)(ws);                               // 8 MB
  _Float16* qb    = (_Float16*)(ws + (8u << 20));                  // 8 MB
  _Float16* aob   = (_Float16*)(ws + (16u << 20));                 // 8 MB
  _Float16* kb    = (_Float16*)(ws + (24u << 20));                 // 512 KB
  _Float16* vtb   = (_Float16*)(ws + (24u << 20) + (512u << 10));  // 512 KB
  _Float16* wcomb = (_Float16*)(ws + (25u << 20));                 // 2.25 MB
  _Float16* woutb = (_Float16*)(ws + (27u << 20) + (512u << 10));  // 2 MB
  float*    bcomb = (float*)(ws + (29u << 20) + (512u << 10));     // 4.6 KB

  hipLaunchKernelGGL(prep_all, dim3(6656), dim3(256), 0, stream,
                     x, wqkv, bqkv, wout, xb, wcomb, woutb, bcomb);
  hipLaunchKernelGGL((gemm_t4<0>), dim3(64, 9), dim3(256), 0, stream,
                     xb, wcomb, bcomb, (void*)qb, kb, vtb);
  hipLaunchKernelGGL(flash_attn14, dim3(512), dim3(512), 0, stream,
                     qb, kb, vtb, aob);
  hipLaunchKernelGGL((gemm_t4<1>), dim3(64, 8), dim3(256), 0, stream,
                     aob, woutb, bout, (void*)out, nullptr, nullptr);
}

// Round 11
// 158.453 us; speedup vs baseline: 1.0851x; 1.0283x over previous
//
#include <hip/hip_runtime.h>

// Problem: B=2, S=2048, D=1024, H=16, HD=64. fp32 in/out.
// Pipeline exploits head-summed K/V: k_sum = x @ (sum_h Wk_h)^T + sum_h bk_h.
//  1. prep_all:    x, Wout -> f16; wcomb = [Wq; Wred] f16 (1152x1024); bcomb
//  2. gemm_t5<0>:  [Q*scale | k_sum | v_sum^T-permuted] = x @ wcomb^T + bcomb
//  3. flash_attn14: register-only P handoff (sigma-permuted V), K/V double-
//                  buffered staging, 1 barrier/tile. AT FLOOR (r8-r10).
//  4. gemm_t5<1>:  out = ao @ Wout^T + bout   (4096x1024x1024) -> f32
// gemm_t5 = 64M x 64N tiles (4 waves, 16-col strip/wave), grids 1152/1024
// blocks -> ~4.5-6 resident blocks/CU. Attacks the m102 small-N TLP
// starvation (90-320 TF at N=1024-2048) that r6/r7 (<=2.25 blk/CU) missed.

#define S_LEN 2048
#define DIM 1024

using floatx4 = __attribute__((ext_vector_type(4))) float;
using halfx8  = __attribute__((ext_vector_type(8))) _Float16;
using halfx4  = __attribute__((ext_vector_type(4))) _Float16;
using halfx2  = __attribute__((ext_vector_type(2))) _Float16;
using fp16x2  = __attribute__((ext_vector_type(2))) __fp16;  // cvt_pkrtz ret

__device__ __forceinline__ floatx4 mfma16(halfx8 a, halfx8 b, floatx4 c) {
  return __builtin_amdgcn_mfma_f32_16x16x32_f16(a, b, c, 0, 0, 0);
}

// async global->LDS, 16B per lane; lds dst is wave-uniform base + lane*16
__device__ __forceinline__ void gll16(const void* g, void* l) {
  __builtin_amdgcn_global_load_lds(
      (const __attribute__((address_space(1))) void*)g,
      (__attribute__((address_space(3))) void*)l, 16, 0, 0);
}

// ---------------- prep: conversions + combined weights ----------------
__global__ __launch_bounds__(256) void prep_all(
    const float* __restrict__ x, const float* __restrict__ wqkv,
    const float* __restrict__ bqkv, const float* __restrict__ wout,
    _Float16* __restrict__ xb, _Float16* __restrict__ wcomb,
    _Float16* __restrict__ woutb, float* __restrict__ bcomb) {
  int bx = blockIdx.x;
  if (bx < 6144) {
    size_t i4 = ((size_t)bx * 256 + threadIdx.x) * 4;
    const float* src;
    _Float16* dst;
    size_t off;
    if (i4 < 4194304) { src = x; dst = xb; off = i4; }
    else if (i4 < 5242880) { src = wqkv; dst = wcomb; off = i4 - 4194304; }
    else { src = wout; dst = woutb; off = i4 - 5242880; }
    float4 v = *(const float4*)(src + off);
    halfx4 o;
    o[0] = (_Float16)v.x; o[1] = (_Float16)v.y;
    o[2] = (_Float16)v.z; o[3] = (_Float16)v.w;
    *(halfx4*)(dst + off) = o;
  } else {
    int gid = (bx - 6144) * 256 + threadIdx.x;  // 131072 threads
    int c = gid >> 10, j = gid & 1023;
    int row0 = (c < 64) ? (1024 + c) : (2048 + c - 64);
    float s = 0.f;
#pragma unroll
    for (int h = 0; h < 16; ++h) s += wqkv[(size_t)(row0 + h * 64) * 1024 + j];
    wcomb[(size_t)1024 * 1024 + gid] = (_Float16)s;
    if (gid < 1024) bcomb[gid] = bqkv[gid];
    if (gid < 128) {
      int b0 = (gid < 64) ? (1024 + gid) : (2048 + gid - 64);
      float sb = 0.f;
#pragma unroll
      for (int h = 0; h < 16; ++h) sb += bqkv[b0 + h * 64];
      bcomb[1024 + gid] = sb;
    }
  }
}

// ---- gemm_t5: 64M x 64N tile, BK=64, single-buffer, 2 barriers/step ----
// 4 waves; wave w owns output cols w*16..+15 (4 m-frags x 1 n-frag).
// Staging per wave/K-step: A rows w*16..+15 (2 gll16), W rows w*16..+15
// (2 gll16); XOR col-group swizzle (row r group g at g^(r&7)). LDS 16 KB,
// tiny acc -> up to 6 blocks/CU resident. Grids 1152/1024 blocks.
// MODE 0: N=1152 fused epilogue -> qb (*scale), kb, vtb (V^T, sigma-permuted
// per 128-s-block: p=(2tq+a)*32+q4*8+tf*2+b). MODE 1: f32 out.
template <int MODE>
__global__ __launch_bounds__(256, 6) void gemm_t5(
    const _Float16* __restrict__ A, const _Float16* __restrict__ W,
    const float* __restrict__ bias, void* __restrict__ Cv,
    _Float16* __restrict__ kbo, _Float16* __restrict__ vto) {
  const int K = 1024;
  __shared__ _Float16 As[64][64];  // 8 KB
  __shared__ _Float16 Ws[64][64];  // 8 KB
  int tid = threadIdx.x;
  int lane = tid & 63, w = tid >> 6, ln = lane & 15, q4 = lane >> 4;
  int m0 = blockIdx.x * 64, n0 = blockIdx.y * 64;
  int rr = lane >> 3, gg = ((lane & 7) ^ rr) * 8;  // staging lane row/col
  const _Float16* agp = A + (size_t)(m0 + w * 16 + rr) * K + gg;
  const _Float16* wgp = W + (size_t)(n0 + w * 16 + rr) * K + gg;
  floatx4 acc[4] = {};
  for (int kt = 0; kt < K; kt += 64) {
    __syncthreads();  // readers done with previous tile
    gll16(agp + kt, &As[w * 16][0]);
    gll16(agp + (size_t)8 * K + kt, &As[w * 16 + 8][0]);
    gll16(wgp + kt, &Ws[w * 16][0]);
    gll16(wgp + (size_t)8 * K + kt, &Ws[w * 16 + 8][0]);
    __syncthreads();  // staging visible
#pragma unroll
    for (int kh = 0; kh < 2; ++kh) {
      int sw = ((q4 + 4 * kh) ^ (ln & 7)) * 8;
      halfx8 bf = *(const halfx8*)&Ws[w * 16 + ln][sw];
#pragma unroll
      for (int mf = 0; mf < 4; ++mf) {
        halfx8 af = *(const halfx8*)&As[mf * 16 + ln][sw];
        acc[mf] = mfma16(af, bf, acc[mf]);
      }
    }
  }
  const float qscale = 0.18033688011112042f;  // (1/sqrt(64)) * log2(e)
  int col = n0 + w * 16 + ln;
  float bv = bias[col];
  if constexpr (MODE == 1) {
#pragma unroll
    for (int mf = 0; mf < 4; ++mf)
#pragma unroll
      for (int i = 0; i < 4; ++i) {
        int row = m0 + mf * 16 + q4 * 4 + i;
        ((float*)Cv)[(size_t)row * 1024 + col] = acc[mf][i] + bv;
      }
  } else {
    if (col < 1024) {  // Q, pre-scaled for log2-domain softmax
#pragma unroll
      for (int mf = 0; mf < 4; ++mf)
#pragma unroll
        for (int i = 0; i < 4; ++i) {
          int row = m0 + mf * 16 + q4 * 4 + i;
          ((_Float16*)Cv)[(size_t)row * 1024 + col] =
              (_Float16)((acc[mf][i] + bv) * qscale);
        }
    } else if (col < 1088) {  // k_sum
      int ck = col - 1024;
#pragma unroll
      for (int mf = 0; mf < 4; ++mf)
#pragma unroll
        for (int i = 0; i < 4; ++i) {
          int row = m0 + mf * 16 + q4 * 4 + i;
          kbo[(size_t)row * 64 + ck] = (_Float16)(acc[mf][i] + bv);
        }
    } else {  // v_sum, transposed + sigma-permuted within each 128-s block
      int d = col - 1088;
#pragma unroll
      for (int mf = 0; mf < 4; ++mf) {
        int row0 = m0 + mf * 16 + q4 * 4;  // 4 consecutive s, 4-aligned
        int bb = row0 >> 11, sps = row0 & 2047;
        int blk = sps & ~127, tl = sps & 127;
        // p(t): t=tq*64+tf*16+q4l*4+rem -> p=(2tq+(rem>>1))*32+q4l*8+tf*2+(rem&1)
        int p0 = (tl >> 6) * 64 + ((tl >> 2) & 3) * 8 + ((tl >> 4) & 3) * 2;
        _Float16* basep = &vto[((size_t)((bb << 6) + d)) * S_LEN + blk];
        halfx2 lo, hi;
        lo[0] = (_Float16)(acc[mf][0] + bv);
        lo[1] = (_Float16)(acc[mf][1] + bv);
        hi[0] = (_Float16)(acc[mf][2] + bv);
        hi[1] = (_Float16)(acc[mf][3] + bv);
        *(halfx2*)&basep[p0] = lo;       // rem 0,1 -> a=0
        *(halfx2*)&basep[p0 + 32] = hi;  // rem 2,3 -> a=1
      }
    }
  }
}

// ------- flash v14: v13 + double-buffered K/V staging (1 barrier/tile) -----
// Block = 8 consecutive s-rows (one chunk), 8 waves, 1 wave = 1 full s-row.
// Per 128-t tile: issue stage(it+1, nxt) -> 16 QK MFMA -> batched softmax ->
// 16 lane-local cvt_pkrtz (sigma-permuted V makes PV B-frag lane-local) ->
// 16 PV MFMA -> barrier. Dispatch pairing (r4/r5 model): blocks (i,i+256)
// co-resident; mapping gives every pair 17 staging units. AT FLOOR (r10).
__global__ __launch_bounds__(512, 4) void flash_attn14(
    const _Float16* __restrict__ Qb, const _Float16* __restrict__ kb,
    const _Float16* __restrict__ vtb, _Float16* __restrict__ aob) {
  __shared__ _Float16 Ks[2][128][64];   // 32 KB  K tiles, XOR-swizzled
  __shared__ _Float16 Vt[2][64][128];   // 32 KB  V^T tiles (sigma-permuted)
  int tid = threadIdx.x;
  int lane = tid & 63, w = tid >> 6, ln = lane & 15, q4 = lane >> 4;
  int bx = (int)blockIdx.x;
  int lo = bx & 255;
  int b = lo & 1;                               // batch
  int crow = (bx >> 8) ? (255 - (lo >> 1)) : (lo >> 1);  // row-chunk
  int s0 = crow * 8;
  int s = s0 + w;
  size_t bS = (size_t)b * S_LEN;

  // K staging: wave w covers t-rows w*16..+15; lane: row += lane>>3, grp^row
  int rr = lane >> 3, ggk = ((lane & 7) ^ rr) * 8;
  const _Float16* kgp = kb + (bS + w * 16 + rr) * 64 + ggk;
  // V staging: wave w covers d-rows w*8..+7; lane: row += lane>>4,
  // p-col = half*64 + (vg ^ (row&7))*8, vg = lane&7, half = (lane>>3)&1
  int vr = lane >> 4;
  int vhalf = (lane >> 3) & 1, vg = lane & 7;
  const _Float16* vgp[2];
#pragma unroll
  for (int j = 0; j < 2; ++j) {
    int row = w * 8 + 4 * j + vr;
    vgp[j] = vtb + ((size_t)b * 64 + row) * S_LEN + vhalf * 64 +
             ((vg ^ (row & 7)) * 8);
  }
  int swk0 = (q4 ^ (ln & 7)) * 8;
  int swk1 = ((q4 + 4) ^ (ln & 7)) * 8;

  const _Float16* qp = Qb + (bS + s) * DIM + ln * 64 + q4 * 8;
  halfx8 bq0 = *(const halfx8*)qp, bq1 = *(const halfx8*)(qp + 32);

  float m_run = -1e30f, l_run = 0.f;
  floatx4 oacc[4] = {};
  int nt = (crow >> 4) + 1;

  // prologue: stage tile 0 into buffer 0
  gll16(kgp, &Ks[0][w * 16][0]);
  gll16(kgp + (size_t)8 * 64, &Ks[0][w * 16 + 8][0]);
  gll16(vgp[0], &Vt[0][w * 8][0]);
  gll16(vgp[1], &Vt[0][w * 8 + 4][0]);
  __syncthreads();  // vmcnt drain: tile 0 visible

  for (int it = 0; it < nt; ++it) {
    int cur = it & 1, nxt = cur ^ 1;
    if (it + 1 < nt) {  // prefetch next tile; lands under this tile's compute
      int t1 = (it + 1) << 7;
      gll16(kgp + (size_t)t1 * 64, &Ks[nxt][w * 16][0]);
      gll16(kgp + (size_t)(t1 + 8) * 64, &Ks[nxt][w * 16 + 8][0]);
      gll16(vgp[0] + t1, &Vt[nxt][w * 8][0]);
      gll16(vgp[1] + t1, &Vt[nxt][w * 8 + 4][0]);
    }
    int t0 = it << 7;

    // S^T = K Q^T (log2 domain): frag (tq,tf) rows t = t0+tq*64+tf*16+ln
    floatx4 sf[2][4];
    __builtin_amdgcn_s_setprio(1);
#pragma unroll
    for (int tq = 0; tq < 2; ++tq)
#pragma unroll
      for (int tf = 0; tf < 4; ++tf) {
        halfx8 ak0 = *(const halfx8*)&Ks[cur][tq * 64 + tf * 16 + ln][swk0];
        halfx8 ak1 = *(const halfx8*)&Ks[cur][tq * 64 + tf * 16 + ln][swk1];
        floatx4 z = {};
        z = mfma16(ak0, bq0, z);
        sf[tq][tf] = mfma16(ak1, bq1, z);
      }
    __builtin_amdgcn_s_setprio(0);
    if (it == nt - 1) {  // causal mask (block-uniform: only final tile)
#pragma unroll
      for (int tq = 0; tq < 2; ++tq)
#pragma unroll
        for (int tf = 0; tf < 4; ++tf)
#pragma unroll
          for (int i = 0; i < 4; ++i) {
            int t = t0 + tq * 64 + tf * 16 + q4 * 4 + i;
            if (t > s) sf[tq][tf][i] = -1e30f;
          }
    }
    // batched max over all 32 values
    float tm = -1e30f;
#pragma unroll
    for (int tq = 0; tq < 2; ++tq)
#pragma unroll
      for (int tf = 0; tf < 4; ++tf)
        tm = fmaxf(tm, fmaxf(fmaxf(sf[tq][tf][0], sf[tq][tf][1]),
                             fmaxf(sf[tq][tf][2], sf[tq][tf][3])));
    tm = fmaxf(tm, __shfl_xor(tm, 16));
    tm = fmaxf(tm, __shfl_xor(tm, 32));
    // defer-rescale (T13): skip O/l rescale while max drift <= 8 (log2)
    if (!__all(tm <= m_run + 8.f)) {
      float mn = fmaxf(m_run, tm);
      float alpha = exp2f(m_run - mn);
      m_run = mn;
      l_run *= alpha;
#pragma unroll
      for (int n2 = 0; n2 < 4; ++n2)
#pragma unroll
        for (int i = 0; i < 4; ++i) oacc[n2][i] *= alpha;
    }
    // exp2 + lane-local PV B-frag build: bp[2tq+a] word tf = pkrtz(p2a,p2a+1)
    float rs = 0.f;
    unsigned bpw[4][4];
#pragma unroll
    for (int tq = 0; tq < 2; ++tq)
#pragma unroll
      for (int tf = 0; tf < 4; ++tf) {
        float p0 = exp2f(sf[tq][tf][0] - m_run);
        float p1 = exp2f(sf[tq][tf][1] - m_run);
        float p2 = exp2f(sf[tq][tf][2] - m_run);
        float p3 = exp2f(sf[tq][tf][3] - m_run);
        rs += (p0 + p1) + (p2 + p3);
        union { fp16x2 h; unsigned u; } c0, c1;
        c0.h = __builtin_amdgcn_cvt_pkrtz(p0, p1);
        c1.h = __builtin_amdgcn_cvt_pkrtz(p2, p3);
        bpw[2 * tq][tf] = c0.u;
        bpw[2 * tq + 1][tf] = c1.u;
      }
    rs += __shfl_xor(rs, 16);
    rs += __shfl_xor(rs, 32);
    l_run += rs;
    // PV: O^T += V^T x P over 4 k-chunks of 32 t (sigma-order, reg operand)
    __builtin_amdgcn_s_setprio(1);
#pragma unroll
    for (int kc = 0; kc < 4; ++kc) {
      union { unsigned u[4]; halfx8 v; } bpu;
#pragma unroll
      for (int ww = 0; ww < 4; ++ww) bpu.u[ww] = bpw[kc][ww];
      int half = (kc >> 1) * 64;
      int sw = ((q4 + 4 * (kc & 1)) ^ (ln & 7)) * 8;
#pragma unroll
      for (int n2 = 0; n2 < 4; ++n2) {
        halfx8 av = *(const halfx8*)&Vt[cur][n2 * 16 + ln][half + sw];
        oacc[n2] = mfma16(av, bpu.v, oacc[n2]);
      }
    }
    __builtin_amdgcn_s_setprio(0);
    // one barrier per tile: drains prefetch (landed under compute) and
    // guards buffer[cur] against overwrite by stage(it+2)
    __syncthreads();
  }
  // epilogue: O^T frag n2: h=ln, d=n2*16+q4*4+i (wave owns the full row)
  float inv = 1.0f / l_run;
#pragma unroll
  for (int n2 = 0; n2 < 4; ++n2) {
    halfx4 o;
#pragma unroll
    for (int i = 0; i < 4; ++i) o[i] = (_Float16)(oacc[n2][i] * inv);
    *(halfx4*)(aob + (bS + s) * DIM + ln * 64 + n2 * 16 + q4 * 4) = o;
  }
}

extern "C" void kernel_launch(void* const* d_in, const int* in_sizes, int n_in,
                              void* d_out, int out_size, void* d_ws,
                              size_t ws_size, hipStream_t stream) {
  const float* x    = (const float*)d_in[0];
  const float* wqkv = (const float*)d_in[1];
  const float* bqkv = (const float*)d_in[2];
  const float* wout = (const float*)d_in[3];
  const float* bout = (const float*)d_in[4];
  float* out = (float*)d_out;
  char* ws = (char*)d_ws;
  _Float16* xb    = (_Float16*)(ws);                               // 8 MB
  _Float16* qb    = (_Float16*)(ws + (8u << 20));                  // 8 MB
  _Float16* aob   = (_Float16*)(ws + (16u << 20));                 // 8 MB
  _Float16* kb    = (_Float16*)(ws + (24u << 20));                 // 512 KB
  _Float16* vtb   = (_Float16*)(ws + (24u << 20) + (512u << 10));  // 512 KB
  _Float16* wcomb = (_Float16*)(ws + (25u << 20));                 // 2.25 MB
  _Float16* woutb = (_Float16*)(ws + (27u << 20) + (512u << 10));  // 2 MB
  float*    bcomb = (float*)(ws + (29u << 20) + (512u << 10));     // 4.6 KB

  hipLaunchKernelGGL(prep_all, dim3(6656), dim3(256), 0, stream,
                     x, wqkv, bqkv, wout, xb, wcomb, woutb, bcomb);
  hipLaunchKernelGGL((gemm_t5<0>), dim3(64, 18), dim3(256), 0, stream,
                     xb, wcomb, bcomb, (void*)qb, kb, vtb);
  hipLaunchKernelGGL(flash_attn14, dim3(512), dim3(512), 0, stream,
                     qb, kb, vtb, aob);
  hipLaunchKernelGGL((gemm_t5<1>), dim3(64, 16), dim3(256), 0, stream,
                     aob, woutb, bout, (void*)out, nullptr, nullptr);
}

// Round 12
// 157.196 us; speedup vs baseline: 1.0938x; 1.0080x over previous
//
#include <hip/hip_runtime.h>

// Problem: B=2, S=2048, D=1024, H=16, HD=64. fp32 in/out.
// Pipeline exploits head-summed K/V: k_sum = x @ (sum_h Wk_h)^T + sum_h bk_h.
//  1. prep_all:    x, Wout -> f16; wcomb = [Wq; Wred] f16 (1152x1024); bcomb
//  2. gemm_t5<0>:  [Q*scale | k_sum | v_sum^T-permuted] = x @ wcomb^T + bcomb
//  3. flash_attn15: 4-row blocks, 4 waves (1 wave = 1 full s-row), grid 1024
//                  -> 4 co-resident blocks/CU (4 independent barrier groups
//                  hide staging latency). Quad-balanced crow mapping: every
//                  co-resident quad (i,i+256,i+512,i+768) carries 34 units.
//                  Register-only P handoff (sigma-permuted V), 32 KB LDS.
//  4. gemm_t5<1>:  out = ao @ Wout^T + bout   (4096x1024x1024) -> f32

#define S_LEN 2048
#define DIM 1024

using floatx4 = __attribute__((ext_vector_type(4))) float;
using halfx8  = __attribute__((ext_vector_type(8))) _Float16;
using halfx4  = __attribute__((ext_vector_type(4))) _Float16;
using halfx2  = __attribute__((ext_vector_type(2))) _Float16;
using fp16x2  = __attribute__((ext_vector_type(2))) __fp16;  // cvt_pkrtz ret

__device__ __forceinline__ floatx4 mfma16(halfx8 a, halfx8 b, floatx4 c) {
  return __builtin_amdgcn_mfma_f32_16x16x32_f16(a, b, c, 0, 0, 0);
}

// async global->LDS, 16B per lane; lds dst is wave-uniform base + lane*16
__device__ __forceinline__ void gll16(const void* g, void* l) {
  __builtin_amdgcn_global_load_lds(
      (const __attribute__((address_space(1))) void*)g,
      (__attribute__((address_space(3))) void*)l, 16, 0, 0);
}

// ---------------- prep: conversions + combined weights ----------------
__global__ __launch_bounds__(256) void prep_all(
    const float* __restrict__ x, const float* __restrict__ wqkv,
    const float* __restrict__ bqkv, const float* __restrict__ wout,
    _Float16* __restrict__ xb, _Float16* __restrict__ wcomb,
    _Float16* __restrict__ woutb, float* __restrict__ bcomb) {
  int bx = blockIdx.x;
  if (bx < 6144) {
    size_t i4 = ((size_t)bx * 256 + threadIdx.x) * 4;
    const float* src;
    _Float16* dst;
    size_t off;
    if (i4 < 4194304) { src = x; dst = xb; off = i4; }
    else if (i4 < 5242880) { src = wqkv; dst = wcomb; off = i4 - 4194304; }
    else { src = wout; dst = woutb; off = i4 - 5242880; }
    float4 v = *(const float4*)(src + off);
    halfx4 o;
    o[0] = (_Float16)v.x; o[1] = (_Float16)v.y;
    o[2] = (_Float16)v.z; o[3] = (_Float16)v.w;
    *(halfx4*)(dst + off) = o;
  } else {
    int gid = (bx - 6144) * 256 + threadIdx.x;  // 131072 threads
    int c = gid >> 10, j = gid & 1023;
    int row0 = (c < 64) ? (1024 + c) : (2048 + c - 64);
    float s = 0.f;
#pragma unroll
    for (int h = 0; h < 16; ++h) s += wqkv[(size_t)(row0 + h * 64) * 1024 + j];
    wcomb[(size_t)1024 * 1024 + gid] = (_Float16)s;
    if (gid < 1024) bcomb[gid] = bqkv[gid];
    if (gid < 128) {
      int b0 = (gid < 64) ? (1024 + gid) : (2048 + gid - 64);
      float sb = 0.f;
#pragma unroll
      for (int h = 0; h < 16; ++h) sb += bqkv[b0 + h * 64];
      bcomb[1024 + gid] = sb;
    }
  }
}

// ---- gemm_t5: 64M x 64N tile, BK=64, single-buffer, 2 barriers/step ----
// 4 waves; wave w owns output cols w*16..+15 (4 m-frags x 1 n-frag).
// Staging per wave/K-step: A rows w*16..+15 (2 gll16), W rows w*16..+15
// (2 gll16); XOR col-group swizzle (row r group g at g^(r&7)). LDS 16 KB,
// tiny acc -> up to 6 blocks/CU resident. Grids 1152/1024 blocks.
// MODE 0: N=1152 fused epilogue -> qb (*scale), kb, vtb (V^T, sigma-permuted
// per 128-s-block: p=(2tq+a)*32+q4*8+tf*2+b). MODE 1: f32 out.
template <int MODE>
__global__ __launch_bounds__(256, 6) void gemm_t5(
    const _Float16* __restrict__ A, const _Float16* __restrict__ W,
    const float* __restrict__ bias, void* __restrict__ Cv,
    _Float16* __restrict__ kbo, _Float16* __restrict__ vto) {
  const int K = 1024;
  __shared__ _Float16 As[64][64];  // 8 KB
  __shared__ _Float16 Ws[64][64];  // 8 KB
  int tid = threadIdx.x;
  int lane = tid & 63, w = tid >> 6, ln = lane & 15, q4 = lane >> 4;
  int m0 = blockIdx.x * 64, n0 = blockIdx.y * 64;
  int rr = lane >> 3, gg = ((lane & 7) ^ rr) * 8;  // staging lane row/col
  const _Float16* agp = A + (size_t)(m0 + w * 16 + rr) * K + gg;
  const _Float16* wgp = W + (size_t)(n0 + w * 16 + rr) * K + gg;
  floatx4 acc[4] = {};
  for (int kt = 0; kt < K; kt += 64) {
    __syncthreads();  // readers done with previous tile
    gll16(agp + kt, &As[w * 16][0]);
    gll16(agp + (size_t)8 * K + kt, &As[w * 16 + 8][0]);
    gll16(wgp + kt, &Ws[w * 16][0]);
    gll16(wgp + (size_t)8 * K + kt, &Ws[w * 16 + 8][0]);
    __syncthreads();  // staging visible
#pragma unroll
    for (int kh = 0; kh < 2; ++kh) {
      int sw = ((q4 + 4 * kh) ^ (ln & 7)) * 8;
      halfx8 bf = *(const halfx8*)&Ws[w * 16 + ln][sw];
#pragma unroll
      for (int mf = 0; mf < 4; ++mf) {
        halfx8 af = *(const halfx8*)&As[mf * 16 + ln][sw];
        acc[mf] = mfma16(af, bf, acc[mf]);
      }
    }
  }
  const float qscale = 0.18033688011112042f;  // (1/sqrt(64)) * log2(e)
  int col = n0 + w * 16 + ln;
  float bv = bias[col];
  if constexpr (MODE == 1) {
#pragma unroll
    for (int mf = 0; mf < 4; ++mf)
#pragma unroll
      for (int i = 0; i < 4; ++i) {
        int row = m0 + mf * 16 + q4 * 4 + i;
        ((float*)Cv)[(size_t)row * 1024 + col] = acc[mf][i] + bv;
      }
  } else {
    if (col < 1024) {  // Q, pre-scaled for log2-domain softmax
#pragma unroll
      for (int mf = 0; mf < 4; ++mf)
#pragma unroll
        for (int i = 0; i < 4; ++i) {
          int row = m0 + mf * 16 + q4 * 4 + i;
          ((_Float16*)Cv)[(size_t)row * 1024 + col] =
              (_Float16)((acc[mf][i] + bv) * qscale);
        }
    } else if (col < 1088) {  // k_sum
      int ck = col - 1024;
#pragma unroll
      for (int mf = 0; mf < 4; ++mf)
#pragma unroll
        for (int i = 0; i < 4; ++i) {
          int row = m0 + mf * 16 + q4 * 4 + i;
          kbo[(size_t)row * 64 + ck] = (_Float16)(acc[mf][i] + bv);
        }
    } else {  // v_sum, transposed + sigma-permuted within each 128-s block
      int d = col - 1088;
#pragma unroll
      for (int mf = 0; mf < 4; ++mf) {
        int row0 = m0 + mf * 16 + q4 * 4;  // 4 consecutive s, 4-aligned
        int bb = row0 >> 11, sps = row0 & 2047;
        int blk = sps & ~127, tl = sps & 127;
        // p(t): t=tq*64+tf*16+q4l*4+rem -> p=(2tq+(rem>>1))*32+q4l*8+tf*2+(rem&1)
        int p0 = (tl >> 6) * 64 + ((tl >> 2) & 3) * 8 + ((tl >> 4) & 3) * 2;
        _Float16* basep = &vto[((size_t)((bb << 6) + d)) * S_LEN + blk];
        halfx2 lo, hi;
        lo[0] = (_Float16)(acc[mf][0] + bv);
        lo[1] = (_Float16)(acc[mf][1] + bv);
        hi[0] = (_Float16)(acc[mf][2] + bv);
        hi[1] = (_Float16)(acc[mf][3] + bv);
        *(halfx2*)&basep[p0] = lo;       // rem 0,1 -> a=0
        *(halfx2*)&basep[p0 + 32] = hi;  // rem 2,3 -> a=1
      }
    }
  }
}

// ------- flash v15: 4-row blocks, grid 1024, 4 barrier groups per CU -------
// Block = 4 consecutive s-rows (one chunk), 4 waves, 1 wave = 1 full s-row.
// Per 128-t tile: stage (8 gll16/wave: 4 K rowsets + 4 V rowsets) -> 16 QK
// MFMA -> batched softmax -> 16 lane-local cvt_pkrtz (sigma-permuted V) ->
// 16 PV MFMA. Single-buffered 32 KB LDS. Dispatch model (r4/r5-validated,
// double round-robin): co-resident quad = (i, i+256, i+512, i+768). Mapping
// q=bx>>8, p=(bx&255)>>1: crow = {p, 255-p, 256+p, 511-p}[q] -> every quad
// carries exactly 34 staging units; bijective over 512 chunks x 2 batches.
__global__ __launch_bounds__(256, 4) void flash_attn15(
    const _Float16* __restrict__ Qb, const _Float16* __restrict__ kb,
    const _Float16* __restrict__ vtb, _Float16* __restrict__ aob) {
  __shared__ _Float16 Ks[128][64];   // 16 KB  K tile [t][d], XOR-swizzled
  __shared__ _Float16 Vt[64][128];   // 16 KB  V^T tile [d][p] (sigma-perm)
  int tid = threadIdx.x;
  int lane = tid & 63, w = tid >> 6, ln = lane & 15, q4 = lane >> 4;
  int bx = (int)blockIdx.x;
  int q = bx >> 8, lo = bx & 255;
  int b = lo & 1, p = lo >> 1;
  int crow = (q == 0) ? p : (q == 1) ? (255 - p) : (q == 2) ? (256 + p)
                                                            : (511 - p);
  int s0 = crow * 4;
  int s = s0 + w;
  size_t bS = (size_t)b * S_LEN;

  // K staging: wave w covers t-rows w*32..+31; lane: row += lane>>3, grp^row
  int rr = lane >> 3, ggk = ((lane & 7) ^ rr) * 8;
  const _Float16* kgp = kb + (bS + w * 32 + rr) * 64 + ggk;
  // V staging: wave w covers d-rows w*16..+15; lane: row += lane>>4,
  // p-col = half*64 + (vg ^ (row&7))*8, vg = lane&7, half = (lane>>3)&1
  int vr = lane >> 4;
  int vhalf = (lane >> 3) & 1, vg = lane & 7;
  const _Float16* vgp[4];
#pragma unroll
  for (int j = 0; j < 4; ++j) {
    int row = w * 16 + 4 * j + vr;
    vgp[j] = vtb + ((size_t)b * 64 + row) * S_LEN + vhalf * 64 +
             ((vg ^ (row & 7)) * 8);
  }
  int swk0 = (q4 ^ (ln & 7)) * 8;
  int swk1 = ((q4 + 4) ^ (ln & 7)) * 8;

  const _Float16* qp = Qb + (bS + s) * DIM + ln * 64 + q4 * 8;
  halfx8 bq0 = *(const halfx8*)qp, bq1 = *(const halfx8*)(qp + 32);

  float m_run = -1e30f, l_run = 0.f;
  floatx4 oacc[4] = {};
  int nt = (crow >> 5) + 1;

  for (int it = 0; it < nt; ++it) {
    int t0 = it << 7;
    __syncthreads();
#pragma unroll
    for (int j = 0; j < 4; ++j)
      gll16(kgp + (size_t)(t0 + 8 * j) * 64, &Ks[w * 32 + 8 * j][0]);
#pragma unroll
    for (int j = 0; j < 4; ++j)
      gll16(vgp[j] + t0, &Vt[w * 16 + 4 * j][0]);
    __syncthreads();

    // S^T = K Q^T (log2 domain): frag (tq,tf) rows t = t0+tq*64+tf*16+ln
    floatx4 sf[2][4];
    __builtin_amdgcn_s_setprio(1);
#pragma unroll
    for (int tq = 0; tq < 2; ++tq)
#pragma unroll
      for (int tf = 0; tf < 4; ++tf) {
        halfx8 ak0 = *(const halfx8*)&Ks[tq * 64 + tf * 16 + ln][swk0];
        halfx8 ak1 = *(const halfx8*)&Ks[tq * 64 + tf * 16 + ln][swk1];
        floatx4 z = {};
        z = mfma16(ak0, bq0, z);
        sf[tq][tf] = mfma16(ak1, bq1, z);
      }
    __builtin_amdgcn_s_setprio(0);
    if (it == nt - 1) {  // causal mask (block-uniform: only final tile)
#pragma unroll
      for (int tq = 0; tq < 2; ++tq)
#pragma unroll
        for (int tf = 0; tf < 4; ++tf)
#pragma unroll
          for (int i = 0; i < 4; ++i) {
            int t = t0 + tq * 64 + tf * 16 + q4 * 4 + i;
            if (t > s) sf[tq][tf][i] = -1e30f;
          }
    }
    // batched max over all 32 values
    float tm = -1e30f;
#pragma unroll
    for (int tq = 0; tq < 2; ++tq)
#pragma unroll
      for (int tf = 0; tf < 4; ++tf)
        tm = fmaxf(tm, fmaxf(fmaxf(sf[tq][tf][0], sf[tq][tf][1]),
                             fmaxf(sf[tq][tf][2], sf[tq][tf][3])));
    tm = fmaxf(tm, __shfl_xor(tm, 16));
    tm = fmaxf(tm, __shfl_xor(tm, 32));
    // defer-rescale (T13): skip O/l rescale while max drift <= 8 (log2)
    if (!__all(tm <= m_run + 8.f)) {
      float mn = fmaxf(m_run, tm);
      float alpha = exp2f(m_run - mn);
      m_run = mn;
      l_run *= alpha;
#pragma unroll
      for (int n2 = 0; n2 < 4; ++n2)
#pragma unroll
        for (int i = 0; i < 4; ++i) oacc[n2][i] *= alpha;
    }
    // exp2 + lane-local PV B-frag build: bp[2tq+a] word tf = pkrtz(p2a,p2a+1)
    float rs = 0.f;
    unsigned bpw[4][4];
#pragma unroll
    for (int tq = 0; tq < 2; ++tq)
#pragma unroll
      for (int tf = 0; tf < 4; ++tf) {
        float p0 = exp2f(sf[tq][tf][0] - m_run);
        float p1 = exp2f(sf[tq][tf][1] - m_run);
        float p2 = exp2f(sf[tq][tf][2] - m_run);
        float p3 = exp2f(sf[tq][tf][3] - m_run);
        rs += (p0 + p1) + (p2 + p3);
        union { fp16x2 h; unsigned u; } c0, c1;
        c0.h = __builtin_amdgcn_cvt_pkrtz(p0, p1);
        c1.h = __builtin_amdgcn_cvt_pkrtz(p2, p3);
        bpw[2 * tq][tf] = c0.u;
        bpw[2 * tq + 1][tf] = c1.u;
      }
    rs += __shfl_xor(rs, 16);
    rs += __shfl_xor(rs, 32);
    l_run += rs;
    // PV: O^T += V^T x P over 4 k-chunks of 32 t (sigma-order, reg operand)
    __builtin_amdgcn_s_setprio(1);
#pragma unroll
    for (int kc = 0; kc < 4; ++kc) {
      union { unsigned u[4]; halfx8 v; } bpu;
#pragma unroll
      for (int ww = 0; ww < 4; ++ww) bpu.u[ww] = bpw[kc][ww];
      int half = (kc >> 1) * 64;
      int sw = ((q4 + 4 * (kc & 1)) ^ (ln & 7)) * 8;
#pragma unroll
      for (int n2 = 0; n2 < 4; ++n2) {
        halfx8 av = *(const halfx8*)&Vt[n2 * 16 + ln][half + sw];
        oacc[n2] = mfma16(av, bpu.v, oacc[n2]);
      }
    }
    __builtin_amdgcn_s_setprio(0);
  }
  // epilogue: O^T frag n2: h=ln, d=n2*16+q4*4+i (wave owns the full row)
  float inv = 1.0f / l_run;
#pragma unroll
  for (int n2 = 0; n2 < 4; ++n2) {
    halfx4 o;
#pragma unroll
    for (int i = 0; i < 4; ++i) o[i] = (_Float16)(oacc[n2][i] * inv);
    *(halfx4*)(aob + (bS + s) * DIM + ln * 64 + n2 * 16 + q4 * 4) = o;
  }
}

extern "C" void kernel_launch(void* const* d_in, const int* in_sizes, int n_in,
                              void* d_out, int out_size, void* d_ws,
                              size_t ws_size, hipStream_t stream) {
  const float* x    = (const float*)d_in[0];
  const float* wqkv = (const float*)d_in[1];
  const float* bqkv = (const float*)d_in[2];
  const float* wout = (const float*)d_in[3];
  const float* bout = (const float*)d_in[4];
  float* out = (float*)d_out;
  char* ws = (char*)d_ws;
  _Float16* xb    = (_Float16*)(ws);                               // 8 MB
  _Float16* qb    = (_Float16*)(ws + (8u << 20));                  // 8 MB
  _Float16* aob   = (_Float16*)(ws + (16u << 20));                 // 8 MB
  _Float16* kb    = (_Float16*)(ws + (24u << 20));                 // 512 KB
  _Float16* vtb   = (_Float16*)(ws + (24u << 20) + (512u << 10));  // 512 KB
  _Float16* wcomb = (_Float16*)(ws + (25u << 20));                 // 2.25 MB
  _Float16* woutb = (_Float16*)(ws + (27u << 20) + (512u << 10));  // 2 MB
  float*    bcomb = (float*)(ws + (29u << 20) + (512u << 10));     // 4.6 KB

  hipLaunchKernelGGL(prep_all, dim3(6656), dim3(256), 0, stream,
                     x, wqkv, bqkv, wout, xb, wcomb, woutb, bcomb);
  hipLaunchKernelGGL((gemm_t5<0>), dim3(64, 18), dim3(256), 0, stream,
                     xb, wcomb, bcomb, (void*)qb, kb, vtb);
  hipLaunchKernelGGL(flash_attn15, dim3(1024), dim3(256), 0, stream,
                     qb, kb, vtb, aob);
  hipLaunchKernelGGL((gemm_t5<1>), dim3(64, 16), dim3(256), 0, stream,
                     aob, woutb, bout, (void*)out, nullptr, nullptr);
}